// Round 2
// baseline (3369.038 us; speedup 1.0000x reference)
//
#include <hip/hip_runtime.h>
#include <cstdint>
#include <cstddef>

// PiFormerBlock: x:[4,2048,1024] fp32
//   x = x + linattn(LN1(x)) @ wo ;  x = x + gelu_lut(LN2(x) @ w1) @ w2
// All-fp32 correctness baseline. GEMMs: 64x64 LDS-tiled, 4x4/thread.
// ws layout (floats): xn[8M] phiq[8M] phik/attn[8M] vbuf[8M] kv[256K] z[4K]
//   FFN intermediate (8192x4096) processed in TWO 4096-token chunks, reusing
//   the contiguous phiq+phik region (16M floats) as scratch.
// total ~135.3 MB (prev layout was 257 MB -> workspace overflow -> abort).

#define D_MODEL 1024
#define SEQ     2048
#define BATCH   4
#define NTOK    8192
#define NHEADS  16
#define DH      64
#define DFF     4096

__device__ __forceinline__ float phi_act(float x) {
  // jax.nn.elu(x)+1 = x>0 ? x+1 : exp(x)
  return x > 0.f ? x + 1.f : expf(x);
}

__device__ __forceinline__ float gelu_lut(float x) {
  // idx = clip(round(x/0.1)+128, 0, 255); v=(idx-128)*0.1; tanh-gelu(v)
  float r = rintf(x / 0.1f);             // round-half-even, matches jnp.round
  r = fminf(fmaxf(r, -128.f), 127.f);
  float v = r * 0.1f;
  float c = 0.7978845608028654f;         // sqrt(2/pi)
  float t = tanhf(c * (v + 0.044715f * v * v * v));
  return 0.5f * v * (1.f + t);
}

// ---------------- LayerNorm over last dim (1024), one block per token ------
__global__ __launch_bounds__(256) void ln_kernel(const float* __restrict__ X,
                                                 const float* __restrict__ g,
                                                 const float* __restrict__ b,
                                                 float* __restrict__ Y) {
  int tok = blockIdx.x;
  int t = threadIdx.x;
  const float4* xr = (const float4*)(X + (size_t)tok * D_MODEL);
  float4 v = xr[t];
  float s  = v.x + v.y + v.z + v.w;
  float s2 = v.x * v.x + v.y * v.y + v.z * v.z + v.w * v.w;
#pragma unroll
  for (int o = 32; o > 0; o >>= 1) {
    s  += __shfl_down(s, o);
    s2 += __shfl_down(s2, o);
  }
  __shared__ float red[8];
  __shared__ float mu_s, rs_s;
  int wid = t >> 6;
  if ((t & 63) == 0) { red[wid] = s; red[wid + 4] = s2; }
  __syncthreads();
  if (t == 0) {
    float ts  = red[0] + red[1] + red[2] + red[3];
    float ts2 = red[4] + red[5] + red[6] + red[7];
    float mu  = ts * (1.f / D_MODEL);
    float var = ts2 * (1.f / D_MODEL) - mu * mu;
    mu_s = mu;
    rs_s = rsqrtf(var + 1e-5f);
  }
  __syncthreads();
  float mu = mu_s, rs = rs_s;
  float4 gv = ((const float4*)g)[t];
  float4 bv = ((const float4*)b)[t];
  float4 o;
  o.x = (v.x - mu) * rs * gv.x + bv.x;
  o.y = (v.y - mu) * rs * gv.y + bv.y;
  o.z = (v.z - mu) * rs * gv.z + bv.z;
  o.w = (v.w - mu) * rs * gv.w + bv.w;
  ((float4*)(Y + (size_t)tok * D_MODEL))[t] = o;
}

// ---------------- fp32 GEMM C[M,N] = A[M,K]@B[K,N], fused epilogue ---------
// ep: 0 none | 1 elu+1 | 2 +R residual | 3 gelu-LUT
__global__ __launch_bounds__(256) void gemm_ep(const float* __restrict__ A,
                                               const float* __restrict__ B,
                                               float* __restrict__ C,
                                               const float* __restrict__ R,
                                               int N, int K, int ep) {
  __shared__ float As[16][64];  // [k][m]
  __shared__ float Bs[16][64];  // [k][n]
  int t  = threadIdx.x;
  int bn = blockIdx.x, bm = blockIdx.y;
  const float* Ab = A + (size_t)bm * 64 * K;
  const float* Bb = B + (size_t)bn * 64;
  int ar = t >> 2, ak = (t & 3) << 2;    // A: row 0..63, k-seg
  int bk = t >> 4, bc = (t & 15) << 2;   // B: k 0..15, col-seg
  int tx = t & 15, ty = t >> 4;
  float acc[4][4] = {};
  for (int k0 = 0; k0 < K; k0 += 16) {
    float4 av = *(const float4*)(Ab + (size_t)ar * K + (k0 + ak));
    float4 bv = *(const float4*)(Bb + (size_t)(k0 + bk) * N + bc);
    __syncthreads();
    As[ak + 0][ar] = av.x;
    As[ak + 1][ar] = av.y;
    As[ak + 2][ar] = av.z;
    As[ak + 3][ar] = av.w;
    *(float4*)&Bs[bk][bc] = bv;
    __syncthreads();
#pragma unroll
    for (int kk = 0; kk < 16; ++kk) {
      float4 a = *(const float4*)&As[kk][ty << 2];
      float4 b = *(const float4*)&Bs[kk][tx << 2];
      acc[0][0] += a.x * b.x; acc[0][1] += a.x * b.y; acc[0][2] += a.x * b.z; acc[0][3] += a.x * b.w;
      acc[1][0] += a.y * b.x; acc[1][1] += a.y * b.y; acc[1][2] += a.y * b.z; acc[1][3] += a.y * b.w;
      acc[2][0] += a.z * b.x; acc[2][1] += a.z * b.y; acc[2][2] += a.z * b.z; acc[2][3] += a.z * b.w;
      acc[3][0] += a.w * b.x; acc[3][1] += a.w * b.y; acc[3][2] += a.w * b.z; acc[3][3] += a.w * b.w;
    }
  }
  size_t row0 = (size_t)bm * 64 + (ty << 2);
  int col0 = (bn << 6) + (tx << 2);
#pragma unroll
  for (int i = 0; i < 4; ++i) {
    float* cp = C + (row0 + i) * N + col0;
    float4 o;
    if (ep == 1) {
      o.x = phi_act(acc[i][0]); o.y = phi_act(acc[i][1]);
      o.z = phi_act(acc[i][2]); o.w = phi_act(acc[i][3]);
    } else if (ep == 2) {
      float4 rv = *(const float4*)(R + (row0 + i) * N + col0);
      o.x = rv.x + acc[i][0]; o.y = rv.y + acc[i][1];
      o.z = rv.z + acc[i][2]; o.w = rv.w + acc[i][3];
    } else if (ep == 3) {
      o.x = gelu_lut(acc[i][0]); o.y = gelu_lut(acc[i][1]);
      o.z = gelu_lut(acc[i][2]); o.w = gelu_lut(acc[i][3]);
    } else {
      o.x = acc[i][0]; o.y = acc[i][1]; o.z = acc[i][2]; o.w = acc[i][3];
    }
    *(float4*)cp = o;
  }
}

// ---------------- kv[b,h,d,e] = sum_s phik[b,s,h,d]*v[b,s,h,e]; z = sum_s phik
__global__ __launch_bounds__(256) void kvz_kernel(const float* __restrict__ PK,
                                                  const float* __restrict__ V,
                                                  float* __restrict__ KV,
                                                  float* __restrict__ Z) {
  int bh = blockIdx.x;
  int b = bh >> 4, h = bh & 15;
  __shared__ float pk[8][64];
  __shared__ float vv[8][64];
  int t = threadIdx.x;
  const size_t base = ((size_t)b * SEQ) * D_MODEL + h * DH;
  int u = t & 127;
  int lrow = u >> 4;           // 0..7
  int lcol = (u & 15) << 2;    // 0..60
  bool isV = (t >= 128);
  const float* src = isV ? V : PK;
  int dkb = (t >> 4) << 2;     // 0..60
  int deb = (t & 15) << 2;     // 0..60
  float acc[4][4] = {};
  float zacc = 0.f;
  for (int s0 = 0; s0 < SEQ; s0 += 8) {
    float4 ld = *(const float4*)(src + base + (size_t)(s0 + lrow) * D_MODEL + lcol);
    __syncthreads();
    if (isV) *(float4*)&vv[lrow][lcol] = ld;
    else     *(float4*)&pk[lrow][lcol] = ld;
    __syncthreads();
#pragma unroll
    for (int ss = 0; ss < 8; ++ss) {
      float4 a  = *(const float4*)&pk[ss][dkb];
      float4 bb = *(const float4*)&vv[ss][deb];
      acc[0][0] += a.x * bb.x; acc[0][1] += a.x * bb.y; acc[0][2] += a.x * bb.z; acc[0][3] += a.x * bb.w;
      acc[1][0] += a.y * bb.x; acc[1][1] += a.y * bb.y; acc[1][2] += a.y * bb.z; acc[1][3] += a.y * bb.w;
      acc[2][0] += a.z * bb.x; acc[2][1] += a.z * bb.y; acc[2][2] += a.z * bb.z; acc[2][3] += a.z * bb.w;
      acc[3][0] += a.w * bb.x; acc[3][1] += a.w * bb.y; acc[3][2] += a.w * bb.z; acc[3][3] += a.w * bb.w;
    }
    if (t < 64) {
#pragma unroll
      for (int ss = 0; ss < 8; ++ss) zacc += pk[ss][t];
    }
  }
  size_t kvbase = (size_t)bh * (DH * DH);
#pragma unroll
  for (int i = 0; i < 4; ++i) {
    float4 o; o.x = acc[i][0]; o.y = acc[i][1]; o.z = acc[i][2]; o.w = acc[i][3];
    *(float4*)(KV + kvbase + (size_t)(dkb + i) * DH + deb) = o;
  }
  if (t < 64) Z[(size_t)bh * DH + t] = zacc;
}

// ---------------- attn[tok, h*64+e] = (phiq[tok,h]·kv[b,h,:,e]) / (phiq·z + 1e-6)
// one block = (b, h, 64-token tile): 64x64x64 mini-GEMM
__global__ __launch_bounds__(256) void attn_kernel(const float* __restrict__ PQ,
                                                   const float* __restrict__ KVm,
                                                   const float* __restrict__ Z,
                                                   float* __restrict__ OUT) {
  int s0 = blockIdx.x << 6;
  int h = blockIdx.y, b = blockIdx.z;
  __shared__ float Pqt[64][64];  // [d][tok]
  __shared__ float Kv[64][64];   // [d][e]
  __shared__ float den[64];
  __shared__ float zsh[64];
  int t = threadIdx.x;
  size_t qbase  = ((size_t)b * SEQ + s0) * D_MODEL + h * DH;
  size_t kvbase = (size_t)(b * NHEADS + h) * (DH * DH);
  int r0 = t >> 4;           // 0..15
  int c4 = (t & 15) << 2;    // 0..60
#pragma unroll
  for (int rr = 0; rr < 4; ++rr) {
    int row = r0 + (rr << 4);
    *(float4*)&Kv[row][c4] = *(const float4*)(KVm + kvbase + (size_t)row * DH + c4);
    float4 q = *(const float4*)(PQ + qbase + (size_t)row * D_MODEL + c4);
    Pqt[c4 + 0][row] = q.x;
    Pqt[c4 + 1][row] = q.y;
    Pqt[c4 + 2][row] = q.z;
    Pqt[c4 + 3][row] = q.w;
  }
  if (t < 16) *(float4*)&zsh[t << 2] = *(const float4*)(Z + (size_t)(b * NHEADS + h) * DH + (t << 2));
  __syncthreads();
  if (t < 64) {
    float d_ = 1e-6f;
#pragma unroll
    for (int dd = 0; dd < 64; ++dd) d_ += Pqt[dd][t] * zsh[dd];
    den[t] = d_;
  }
  __syncthreads();
  int tokb = (t >> 4) << 2, eb = (t & 15) << 2;
  float acc[4][4] = {};
#pragma unroll 8
  for (int dd = 0; dd < 64; ++dd) {
    float4 a  = *(const float4*)&Pqt[dd][tokb];
    float4 bb = *(const float4*)&Kv[dd][eb];
    acc[0][0] += a.x * bb.x; acc[0][1] += a.x * bb.y; acc[0][2] += a.x * bb.z; acc[0][3] += a.x * bb.w;
    acc[1][0] += a.y * bb.x; acc[1][1] += a.y * bb.y; acc[1][2] += a.y * bb.z; acc[1][3] += a.y * bb.w;
    acc[2][0] += a.z * bb.x; acc[2][1] += a.z * bb.y; acc[2][2] += a.z * bb.z; acc[2][3] += a.z * bb.w;
    acc[3][0] += a.w * bb.x; acc[3][1] += a.w * bb.y; acc[3][2] += a.w * bb.z; acc[3][3] += a.w * bb.w;
  }
#pragma unroll
  for (int i = 0; i < 4; ++i) {
    float dv = den[tokb + i];
    float4 o;
    o.x = acc[i][0] / dv; o.y = acc[i][1] / dv; o.z = acc[i][2] / dv; o.w = acc[i][3] / dv;
    *(float4*)(OUT + ((size_t)b * SEQ + s0 + tokb + i) * D_MODEL + h * DH + eb) = o;
  }
}

extern "C" void kernel_launch(void* const* d_in, const int* in_sizes, int n_in,
                              void* d_out, int out_size, void* d_ws, size_t ws_size,
                              hipStream_t stream) {
  const float* x    = (const float*)d_in[0];
  const float* ln1g = (const float*)d_in[1];
  const float* ln1b = (const float*)d_in[2];
  const float* wq   = (const float*)d_in[3];
  const float* wk   = (const float*)d_in[4];
  const float* wv   = (const float*)d_in[5];
  const float* wo   = (const float*)d_in[6];
  const float* ln2g = (const float*)d_in[7];
  const float* ln2b = (const float*)d_in[8];
  const float* w1   = (const float*)d_in[9];
  const float* w2   = (const float*)d_in[10];
  float* out = (float*)d_out;
  float* ws  = (float*)d_ws;

  const size_t SLOT = (size_t)NTOK * D_MODEL;  // 8M floats (32 MB)
  float* xn   = ws;             // LN1 out, later LN2 out
  float* phiq = ws + SLOT;
  float* phik = ws + 2 * SLOT;  // later reused as attn output
  float* vbuf = ws + 3 * SLOT;
  float* kv   = ws + 4 * SLOT;                         // 262144 floats
  float* z    = kv + (size_t)BATCH * NHEADS * DH * DH; // 4096 floats
  // peak ws use: 4*SLOT + kv + z  ~= 135.3 MB

  dim3 blk(256);
  dim3 gD(D_MODEL / 64, NTOK / 64);

  // LN1
  ln_kernel<<<NTOK, blk, 0, stream>>>(x, ln1g, ln1b, xn);
  // q,k,v projections (phi fused for q,k)
  gemm_ep<<<gD, blk, 0, stream>>>(xn, wq, phiq, nullptr, D_MODEL, D_MODEL, 1);
  gemm_ep<<<gD, blk, 0, stream>>>(xn, wk, phik, nullptr, D_MODEL, D_MODEL, 1);
  gemm_ep<<<gD, blk, 0, stream>>>(xn, wv, vbuf, nullptr, D_MODEL, D_MODEL, 0);
  // kv, z reductions over S
  kvz_kernel<<<BATCH * NHEADS, blk, 0, stream>>>(phik, vbuf, kv, z);
  // num/den -> attn (reuse phik slot)
  float* attn = phik;
  attn_kernel<<<dim3(SEQ / 64, NHEADS, BATCH), blk, 0, stream>>>(phiq, kv, z, attn);
  // x1 = x + attn@wo  -> out
  gemm_ep<<<gD, blk, 0, stream>>>(attn, wo, out, x, D_MODEL, D_MODEL, 2);
  // LN2
  ln_kernel<<<NTOK, blk, 0, stream>>>(out, ln2g, ln2b, xn);

  // FFN in two 4096-token chunks; scratch = phiq..phik region (16M floats,
  // holds 4096x4096), both dead by now.
  float* fbuf = phiq;
  const int CH = 4096;  // tokens per chunk
  dim3 gF1(DFF / 64, CH / 64);      // h@w1 chunk
  dim3 gF2(D_MODEL / 64, CH / 64);  // ffn@w2 chunk
  for (int c = 0; c < 2; ++c) {
    const float* hA = xn + (size_t)c * CH * D_MODEL;
    float* oC = out + (size_t)c * CH * D_MODEL;
    gemm_ep<<<gF1, blk, 0, stream>>>(hA, w1, fbuf, nullptr, DFF, D_MODEL, 3);
    gemm_ep<<<gF2, blk, 0, stream>>>(fbuf, w2, oC, oC, D_MODEL, DFF, 2);
  }
}

// Round 3
// 782.834 us; speedup vs baseline: 4.3036x; 4.3036x over previous
//
#include <hip/hip_runtime.h>
#include <cstdint>
#include <cstddef>

// PiFormerBlock, MFMA bf16 version.
//   x = x + linattn(LN1(x)) @ wo ;  x = x + gelu_lut(LN2(x) @ w1) @ w2
// GEMMs: 128x128 tile, BK=64, mfma_f32_16x16x32_bf16, global_load_lds(16B),
// XOR-swizzled LDS. Activations hi/lo bf16 split (weights are exact powers of
// two in bf16, so C = (Ah+Al)@W gives ~fp32 accuracy). ffn@w2 single-plane.
//
// ws layout (bytes):
//   0        xn_hi   [8192x1024] bf16 (16MB)   (reused as attn_hi)
//   16MB     xn_lo   (16MB)                    (reused as attn_lo)
//   32MB     phiq    fp32 (32MB)  \__ later overlaid by ffn bf16 [8192x4096] (64MB)
//   64MB     phik    fp32 (32MB)  /
//   96MB     vbuf    fp32 (32MB)  -- later overlaid by w1T (8MB) + w2T (8MB)
//   128MB    woT     bf16 (2MB)
// d_out used as scratch before it is written: wqT/wkT/wvT (6MB), kv+z (@6MB).

#define D_MODEL 1024
#define SEQ     2048
#define BATCH   4
#define NTOK    8192
#define NHEADS  16
#define DH      64
#define DFF     4096

typedef short short8 __attribute__((ext_vector_type(8)));
typedef float f32x4 __attribute__((ext_vector_type(4)));

__device__ __forceinline__ unsigned short f2bf(float x) {
  unsigned u = __float_as_uint(x);
  unsigned r = (u + 0x7FFFu + ((u >> 16) & 1u)) >> 16;
  return (unsigned short)r;
}
__device__ __forceinline__ float bf2f(unsigned short h) {
  return __uint_as_float(((unsigned)h) << 16);
}

__device__ __forceinline__ float phi_act(float x) {
  return x > 0.f ? x + 1.f : expf(x);
}

__device__ __forceinline__ float gelu_lut(float x) {
  float r = rintf(x / 0.1f);
  r = fminf(fmaxf(r, -128.f), 127.f);
  float v = r * 0.1f;
  float c = 0.7978845608028654f;
  float t = tanhf(c * (v + 0.044715f * v * v * v));
  return 0.5f * v * (1.f + t);
}

__device__ __forceinline__ void gl_lds16(const void* g, void* l) {
  __builtin_amdgcn_global_load_lds(
      (const __attribute__((address_space(1))) unsigned int*)g,
      (__attribute__((address_space(3))) unsigned int*)l, 16, 0, 0);
}

// ---------------- transpose-convert: W fp32 [K,N] -> WT bf16 [N,K] ----------
__global__ __launch_bounds__(256) void convT(const float* __restrict__ W,
                                             unsigned short* __restrict__ WT,
                                             int K, int N) {
  __shared__ float tile[64][65];
  int kb = blockIdx.y << 6, nb = blockIdx.x << 6;
  int t = threadIdx.x;
  int rr = t >> 4, cc = (t & 15) << 2;
#pragma unroll
  for (int i = 0; i < 4; ++i) {
    int r = rr + (i << 4);
    float4 v = *(const float4*)(W + (size_t)(kb + r) * N + nb + cc);
    tile[r][cc] = v.x; tile[r][cc + 1] = v.y; tile[r][cc + 2] = v.z; tile[r][cc + 3] = v.w;
  }
  __syncthreads();
#pragma unroll
  for (int i = 0; i < 4; ++i) {
    int n = rr + (i << 4);
    ushort4 o;
    o.x = f2bf(tile[cc + 0][n]); o.y = f2bf(tile[cc + 1][n]);
    o.z = f2bf(tile[cc + 2][n]); o.w = f2bf(tile[cc + 3][n]);
    *(ushort4*)(WT + (size_t)(nb + n) * K + kb + cc) = o;
  }
}

// ---------------- LayerNorm -> hi/lo bf16 planes ---------------------------
__global__ __launch_bounds__(256) void ln_kernel(const float* __restrict__ X,
                                                 const float* __restrict__ g,
                                                 const float* __restrict__ b,
                                                 unsigned short* __restrict__ Yh,
                                                 unsigned short* __restrict__ Yl) {
  int tok = blockIdx.x;
  int t = threadIdx.x;
  const float4* xr = (const float4*)(X + (size_t)tok * D_MODEL);
  float4 v = xr[t];
  float s  = v.x + v.y + v.z + v.w;
  float s2 = v.x * v.x + v.y * v.y + v.z * v.z + v.w * v.w;
#pragma unroll
  for (int o = 32; o > 0; o >>= 1) {
    s  += __shfl_down(s, o);
    s2 += __shfl_down(s2, o);
  }
  __shared__ float red[8];
  __shared__ float mu_s, rs_s;
  int wid = t >> 6;
  if ((t & 63) == 0) { red[wid] = s; red[wid + 4] = s2; }
  __syncthreads();
  if (t == 0) {
    float ts  = red[0] + red[1] + red[2] + red[3];
    float ts2 = red[4] + red[5] + red[6] + red[7];
    float mu  = ts * (1.f / D_MODEL);
    float var = ts2 * (1.f / D_MODEL) - mu * mu;
    mu_s = mu;
    rs_s = rsqrtf(var + 1e-5f);
  }
  __syncthreads();
  float mu = mu_s, rs = rs_s;
  float4 gv = ((const float4*)g)[t];
  float4 bv = ((const float4*)b)[t];
  float o0 = (v.x - mu) * rs * gv.x + bv.x;
  float o1 = (v.y - mu) * rs * gv.y + bv.y;
  float o2 = (v.z - mu) * rs * gv.z + bv.z;
  float o3 = (v.w - mu) * rs * gv.w + bv.w;
  ushort4 hv, lv;
  hv.x = f2bf(o0); lv.x = f2bf(o0 - bf2f(hv.x));
  hv.y = f2bf(o1); lv.y = f2bf(o1 - bf2f(hv.y));
  hv.z = f2bf(o2); lv.z = f2bf(o2 - bf2f(hv.z));
  hv.w = f2bf(o3); lv.w = f2bf(o3 - bf2f(hv.w));
  ((ushort4*)(Yh + (size_t)tok * D_MODEL))[t] = hv;
  ((ushort4*)(Yl + (size_t)tok * D_MODEL))[t] = lv;
}

// ---------------- MFMA GEMM: C[M,N] = (Ah+Al)[M,K] @ BT[N,K]^T -------------
// EP: 0 fp32 | 1 phi fp32 | 2 +R fp32 | 3 gelu-LUT bf16
template <int EP, bool SPLIT>
__global__ __launch_bounds__(256, 2) void mfma_gemm(
    const unsigned short* __restrict__ Ah,
    const unsigned short* __restrict__ Al,
    const unsigned short* __restrict__ BT,
    void* Cv, const float* R, int N, int K) {
  __shared__ unsigned short smem[(SPLIT ? 3 : 2) * 8192];
  unsigned short* sAh = smem;
  unsigned short* sAl = SPLIT ? (smem + 8192) : smem;
  unsigned short* sB  = smem + (SPLIT ? 2 : 1) * 8192;

  int t = threadIdx.x;
  int w = t >> 6, l = t & 63;
  int rl = l >> 3, cl = l & 7;
  int gseg = (cl ^ rl) << 4;        // swizzled 16B segment (bytes)
  int m0 = blockIdx.y << 7;
  int n0 = blockIdx.x << 7;
  size_t strideB = (size_t)K * 2;   // row bytes for A and BT

  const char* gA[4]; const char* gAl[4]; const char* gB[4];
  int ldsOff[4];
  for (int j = 0; j < 4; ++j) {
    int row = (w << 5) + (j << 3) + rl;
    gA[j] = (const char*)Ah + (size_t)(m0 + row) * strideB + gseg;
    if (SPLIT) gAl[j] = (const char*)Al + (size_t)(m0 + row) * strideB + gseg;
    gB[j] = (const char*)BT + (size_t)(n0 + row) * strideB + gseg;
    ldsOff[j] = ((w << 5) + (j << 3)) << 6;  // row0 * 64 shorts
  }

  int wm = w >> 1, wn = w & 1;
  int m16 = l & 15, qd = l >> 4;

  f32x4 acc[4][4];
#pragma unroll
  for (int i = 0; i < 4; ++i)
#pragma unroll
    for (int j = 0; j < 4; ++j) acc[i][j] = (f32x4){0.f, 0.f, 0.f, 0.f};

  for (int k0 = 0; k0 < K; k0 += 64) {
    size_t kb = (size_t)k0 * 2;
#pragma unroll
    for (int j = 0; j < 4; ++j) {
      gl_lds16(gA[j] + kb, sAh + ldsOff[j]);
      if (SPLIT) gl_lds16(gAl[j] + kb, sAl + ldsOff[j]);
      gl_lds16(gB[j] + kb, sB + ldsOff[j]);
    }
    __syncthreads();
#pragma unroll
    for (int kk = 0; kk < 2; ++kk) {
      int ksb = (kk << 2) + qd;
      short8 afh[4], afl[4], bfr[4];
#pragma unroll
      for (int mt = 0; mt < 4; ++mt) {
        int r = (wm << 6) + (mt << 4) + m16;
        int slot = ksb ^ (r & 7);
        afh[mt] = *(const short8*)(sAh + (r << 6) + (slot << 3));
        if (SPLIT) afl[mt] = *(const short8*)(sAl + (r << 6) + (slot << 3));
      }
#pragma unroll
      for (int nt = 0; nt < 4; ++nt) {
        int r = (wn << 6) + (nt << 4) + m16;
        int slot = ksb ^ (r & 7);
        bfr[nt] = *(const short8*)(sB + (r << 6) + (slot << 3));
      }
#pragma unroll
      for (int mt = 0; mt < 4; ++mt)
#pragma unroll
        for (int nt = 0; nt < 4; ++nt) {
          acc[mt][nt] = __builtin_amdgcn_mfma_f32_16x16x32_bf16(afh[mt], bfr[nt], acc[mt][nt], 0, 0, 0);
          if (SPLIT)
            acc[mt][nt] = __builtin_amdgcn_mfma_f32_16x16x32_bf16(afl[mt], bfr[nt], acc[mt][nt], 0, 0, 0);
        }
    }
    __syncthreads();
  }

  int colBase = n0 + (wn << 6) + m16;
#pragma unroll
  for (int mt = 0; mt < 4; ++mt) {
    int rBase = m0 + (wm << 6) + (mt << 4) + (qd << 2);
#pragma unroll
    for (int nt = 0; nt < 4; ++nt) {
      int col = colBase + (nt << 4);
#pragma unroll
      for (int i = 0; i < 4; ++i) {
        size_t idx = (size_t)(rBase + i) * N + col;
        float v = acc[mt][nt][i];
        if (EP == 1)      ((float*)Cv)[idx] = phi_act(v);
        else if (EP == 2) ((float*)Cv)[idx] = R[idx] + v;
        else if (EP == 3) ((unsigned short*)Cv)[idx] = f2bf(gelu_lut(v));
        else              ((float*)Cv)[idx] = v;
      }
    }
  }
}

// ---------------- kv[b,h,d,e] = sum_s phik*v ; z = sum_s phik --------------
__global__ __launch_bounds__(256) void kvz_kernel(const float* __restrict__ PK,
                                                  const float* __restrict__ V,
                                                  float* __restrict__ KV,
                                                  float* __restrict__ Z) {
  int bh = blockIdx.x;
  int b = bh >> 4, h = bh & 15;
  __shared__ float pk[8][64];
  __shared__ float vv[8][64];
  int t = threadIdx.x;
  const size_t base = ((size_t)b * SEQ) * D_MODEL + h * DH;
  int u = t & 127;
  int lrow = u >> 4;
  int lcol = (u & 15) << 2;
  bool isV = (t >= 128);
  const float* src = isV ? V : PK;
  int dkb = (t >> 4) << 2;
  int deb = (t & 15) << 2;
  float acc[4][4] = {};
  float zacc = 0.f;
  for (int s0 = 0; s0 < SEQ; s0 += 8) {
    float4 ld = *(const float4*)(src + base + (size_t)(s0 + lrow) * D_MODEL + lcol);
    __syncthreads();
    if (isV) *(float4*)&vv[lrow][lcol] = ld;
    else     *(float4*)&pk[lrow][lcol] = ld;
    __syncthreads();
#pragma unroll
    for (int ss = 0; ss < 8; ++ss) {
      float4 a  = *(const float4*)&pk[ss][dkb];
      float4 bb = *(const float4*)&vv[ss][deb];
      acc[0][0] += a.x * bb.x; acc[0][1] += a.x * bb.y; acc[0][2] += a.x * bb.z; acc[0][3] += a.x * bb.w;
      acc[1][0] += a.y * bb.x; acc[1][1] += a.y * bb.y; acc[1][2] += a.y * bb.z; acc[1][3] += a.y * bb.w;
      acc[2][0] += a.z * bb.x; acc[2][1] += a.z * bb.y; acc[2][2] += a.z * bb.z; acc[2][3] += a.z * bb.w;
      acc[3][0] += a.w * bb.x; acc[3][1] += a.w * bb.y; acc[3][2] += a.w * bb.z; acc[3][3] += a.w * bb.w;
    }
    if (t < 64) {
#pragma unroll
      for (int ss = 0; ss < 8; ++ss) zacc += pk[ss][t];
    }
  }
  size_t kvbase = (size_t)bh * (DH * DH);
#pragma unroll
  for (int i = 0; i < 4; ++i) {
    float4 o; o.x = acc[i][0]; o.y = acc[i][1]; o.z = acc[i][2]; o.w = acc[i][3];
    *(float4*)(KV + kvbase + (size_t)(dkb + i) * DH + deb) = o;
  }
  if (t < 64) Z[(size_t)bh * DH + t] = zacc;
}

// ---------------- attn -> hi/lo bf16 planes --------------------------------
__global__ __launch_bounds__(256) void attn_kernel(const float* __restrict__ PQ,
                                                   const float* __restrict__ KVm,
                                                   const float* __restrict__ Z,
                                                   unsigned short* __restrict__ Oh,
                                                   unsigned short* __restrict__ Ol) {
  int s0 = blockIdx.x << 6;
  int h = blockIdx.y, b = blockIdx.z;
  __shared__ float Pqt[64][64];
  __shared__ float Kv[64][64];
  __shared__ float den[64];
  __shared__ float zsh[64];
  int t = threadIdx.x;
  size_t qbase  = ((size_t)b * SEQ + s0) * D_MODEL + h * DH;
  size_t kvbase = (size_t)(b * NHEADS + h) * (DH * DH);
  int r0 = t >> 4;
  int c4 = (t & 15) << 2;
#pragma unroll
  for (int rr = 0; rr < 4; ++rr) {
    int row = r0 + (rr << 4);
    *(float4*)&Kv[row][c4] = *(const float4*)(KVm + kvbase + (size_t)row * DH + c4);
    float4 q = *(const float4*)(PQ + qbase + (size_t)row * D_MODEL + c4);
    Pqt[c4 + 0][row] = q.x;
    Pqt[c4 + 1][row] = q.y;
    Pqt[c4 + 2][row] = q.z;
    Pqt[c4 + 3][row] = q.w;
  }
  if (t < 16) *(float4*)&zsh[t << 2] = *(const float4*)(Z + (size_t)(b * NHEADS + h) * DH + (t << 2));
  __syncthreads();
  if (t < 64) {
    float d_ = 1e-6f;
#pragma unroll
    for (int dd = 0; dd < 64; ++dd) d_ += Pqt[dd][t] * zsh[dd];
    den[t] = d_;
  }
  __syncthreads();
  int tokb = (t >> 4) << 2, eb = (t & 15) << 2;
  float acc[4][4] = {};
#pragma unroll 8
  for (int dd = 0; dd < 64; ++dd) {
    float4 a  = *(const float4*)&Pqt[dd][tokb];
    float4 bb = *(const float4*)&Kv[dd][eb];
    acc[0][0] += a.x * bb.x; acc[0][1] += a.x * bb.y; acc[0][2] += a.x * bb.z; acc[0][3] += a.x * bb.w;
    acc[1][0] += a.y * bb.x; acc[1][1] += a.y * bb.y; acc[1][2] += a.y * bb.z; acc[1][3] += a.y * bb.w;
    acc[2][0] += a.z * bb.x; acc[2][1] += a.z * bb.y; acc[2][2] += a.z * bb.z; acc[2][3] += a.z * bb.w;
    acc[3][0] += a.w * bb.x; acc[3][1] += a.w * bb.y; acc[3][2] += a.w * bb.z; acc[3][3] += a.w * bb.w;
  }
#pragma unroll
  for (int i = 0; i < 4; ++i) {
    float dv = den[tokb + i];
    float v0 = acc[i][0] / dv, v1 = acc[i][1] / dv, v2 = acc[i][2] / dv, v3 = acc[i][3] / dv;
    ushort4 hv, lv;
    hv.x = f2bf(v0); lv.x = f2bf(v0 - bf2f(hv.x));
    hv.y = f2bf(v1); lv.y = f2bf(v1 - bf2f(hv.y));
    hv.z = f2bf(v2); lv.z = f2bf(v2 - bf2f(hv.z));
    hv.w = f2bf(v3); lv.w = f2bf(v3 - bf2f(hv.w));
    size_t oidx = ((size_t)b * SEQ + s0 + tokb + i) * D_MODEL + h * DH + eb;
    *(ushort4*)(Oh + oidx) = hv;
    *(ushort4*)(Ol + oidx) = lv;
  }
}

extern "C" void kernel_launch(void* const* d_in, const int* in_sizes, int n_in,
                              void* d_out, int out_size, void* d_ws, size_t ws_size,
                              hipStream_t stream) {
  const float* x    = (const float*)d_in[0];
  const float* ln1g = (const float*)d_in[1];
  const float* ln1b = (const float*)d_in[2];
  const float* wq   = (const float*)d_in[3];
  const float* wk   = (const float*)d_in[4];
  const float* wv   = (const float*)d_in[5];
  const float* wo   = (const float*)d_in[6];
  const float* ln2g = (const float*)d_in[7];
  const float* ln2b = (const float*)d_in[8];
  const float* w1   = (const float*)d_in[9];
  const float* w2   = (const float*)d_in[10];
  float* out = (float*)d_out;
  char* ws = (char*)d_ws;

  const size_t MB = 1024 * 1024;
  unsigned short* xnh  = (unsigned short*)(ws);
  unsigned short* xnl  = (unsigned short*)(ws + 16 * MB);
  float*          phiq = (float*)(ws + 32 * MB);
  float*          phik = (float*)(ws + 64 * MB);
  float*          vbuf = (float*)(ws + 96 * MB);
  unsigned short* ffn  = (unsigned short*)(ws + 32 * MB);   // overlays phiq+phik
  unsigned short* w1T  = (unsigned short*)(ws + 96 * MB);   // overlays vbuf
  unsigned short* w2T  = (unsigned short*)(ws + 104 * MB);
  unsigned short* woT  = (unsigned short*)(ws + 128 * MB);

  // d_out as scratch until wo-GEMM writes it
  unsigned short* wqT = (unsigned short*)d_out;
  unsigned short* wkT = wqT + (size_t)D_MODEL * D_MODEL;
  unsigned short* wvT = wkT + (size_t)D_MODEL * D_MODEL;
  float* kv = out + (6 * MB) / 4;                           // 64*64*64 floats
  float* z  = kv + (size_t)BATCH * NHEADS * DH * DH;

  dim3 blk(256);
  dim3 gcD(D_MODEL / 64, D_MODEL / 64);

  // weight convert+transpose (wq/wk/wv/wo now; w1/w2 later, after vbuf dies)
  convT<<<gcD, blk, 0, stream>>>(wq, wqT, D_MODEL, D_MODEL);
  convT<<<gcD, blk, 0, stream>>>(wk, wkT, D_MODEL, D_MODEL);
  convT<<<gcD, blk, 0, stream>>>(wv, wvT, D_MODEL, D_MODEL);
  convT<<<gcD, blk, 0, stream>>>(wo, woT, D_MODEL, D_MODEL);

  // LN1 -> hi/lo
  ln_kernel<<<NTOK, blk, 0, stream>>>(x, ln1g, ln1b, xnh, xnl);

  dim3 gD(D_MODEL / 128, NTOK / 128);
  // q,k,v projections
  mfma_gemm<1, true><<<gD, blk, 0, stream>>>(xnh, xnl, wqT, phiq, nullptr, D_MODEL, D_MODEL);
  mfma_gemm<1, true><<<gD, blk, 0, stream>>>(xnh, xnl, wkT, phik, nullptr, D_MODEL, D_MODEL);
  mfma_gemm<0, true><<<gD, blk, 0, stream>>>(xnh, xnl, wvT, vbuf, nullptr, D_MODEL, D_MODEL);

  // kv, z
  kvz_kernel<<<BATCH * NHEADS, blk, 0, stream>>>(phik, vbuf, kv, z);
  // attn -> hi/lo planes (reuse xn slots; xn is dead until LN2)
  attn_kernel<<<dim3(SEQ / 64, NHEADS, BATCH), blk, 0, stream>>>(phiq, kv, z, xnh, xnl);

  // w1T/w2T conversions into vbuf region (dead after kvz)
  convT<<<dim3(DFF / 64, D_MODEL / 64), blk, 0, stream>>>(w1, w1T, D_MODEL, DFF);
  convT<<<dim3(D_MODEL / 64, DFF / 64), blk, 0, stream>>>(w2, w2T, DFF, D_MODEL);

  // x1 = x + attn@wo -> out (kv/z scratch in out dead by stream order)
  mfma_gemm<2, true><<<gD, blk, 0, stream>>>(xnh, xnl, woT, out, x, D_MODEL, D_MODEL);

  // LN2 -> hi/lo
  ln_kernel<<<NTOK, blk, 0, stream>>>(out, ln2g, ln2b, xnh, xnl);

  // ffn = gelu_lut(h @ w1) -> bf16
  dim3 gF(DFF / 128, NTOK / 128);
  mfma_gemm<3, true><<<gF, blk, 0, stream>>>(xnh, xnl, w1T, ffn, nullptr, DFF, D_MODEL);

  // out += ffn @ w2 (single-plane bf16 A)
  mfma_gemm<2, false><<<gD, blk, 0, stream>>>(ffn, nullptr, w2T, out, out, D_MODEL, DFF);
}

// Round 4
// 650.907 us; speedup vs baseline: 5.1759x; 1.2027x over previous
//
#include <hip/hip_runtime.h>
#include <cstdint>
#include <cstddef>

// PiFormerBlock, MFMA bf16 version, round 4: parallelized kv/z reduction.
//   x = x + linattn(LN1(x)) @ wo ;  x = x + gelu_lut(LN2(x) @ w1) @ w2
// GEMMs: 128x128 tile, BK=64, mfma_f32_16x16x32_bf16, global_load_lds(16B),
// XOR-swizzled LDS. Activations hi/lo bf16 split. ffn@w2 single-plane.
// kv/z: two-stage S-split reduction (16 chunks x 64 bh -> reduce), replacing
// the 64-block kvz kernel that ran at 2.9% occupancy (170us -> ~20us).
//
// ws layout (bytes):
//   0        xn_hi   [8192x1024] bf16 (16MB)   (reused as attn_hi)
//   16MB     xn_lo   (16MB)                    (reused as attn_lo)
//   32MB     phiq    fp32 (32MB)  \__ later overlaid by ffn bf16 (64MB)
//   64MB     phik    fp32 (32MB)  /
//   96MB     vbuf    fp32 (32MB)  -- later overlaid by w1T (8MB) + w2T (8MB)
//   128MB    woT     bf16 (2MB)
// d_out scratch (dead before wo-GEMM writes it):
//   0MB wqT/wkT/wvT (6MB) | 6MB kv partials (17.04MB) | 24MB kv (1MB) | 25MB z

#define D_MODEL 1024
#define SEQ     2048
#define BATCH   4
#define NTOK    8192
#define NHEADS  16
#define DH      64
#define DFF     4096
#define KVCH    16            // S-chunks for kv partial reduction
#define CHROWS  (SEQ / KVCH)  // 128 seq rows per chunk
#define PSTRIDE 4160          // 64*64 kv + 64 z floats per (chunk,bh)

typedef short short8 __attribute__((ext_vector_type(8)));
typedef float f32x4 __attribute__((ext_vector_type(4)));

__device__ __forceinline__ unsigned short f2bf(float x) {
  unsigned u = __float_as_uint(x);
  unsigned r = (u + 0x7FFFu + ((u >> 16) & 1u)) >> 16;
  return (unsigned short)r;
}
__device__ __forceinline__ float bf2f(unsigned short h) {
  return __uint_as_float(((unsigned)h) << 16);
}

__device__ __forceinline__ float phi_act(float x) {
  return x > 0.f ? x + 1.f : expf(x);
}

__device__ __forceinline__ float gelu_lut(float x) {
  float r = rintf(x / 0.1f);
  r = fminf(fmaxf(r, -128.f), 127.f);
  float v = r * 0.1f;
  float c = 0.7978845608028654f;
  float t = tanhf(c * (v + 0.044715f * v * v * v));
  return 0.5f * v * (1.f + t);
}

__device__ __forceinline__ void gl_lds16(const void* g, void* l) {
  __builtin_amdgcn_global_load_lds(
      (const __attribute__((address_space(1))) unsigned int*)g,
      (__attribute__((address_space(3))) unsigned int*)l, 16, 0, 0);
}

// ---------------- transpose-convert: W fp32 [K,N] -> WT bf16 [N,K] ----------
__global__ __launch_bounds__(256) void convT(const float* __restrict__ W,
                                             unsigned short* __restrict__ WT,
                                             int K, int N) {
  __shared__ float tile[64][65];
  int kb = blockIdx.y << 6, nb = blockIdx.x << 6;
  int t = threadIdx.x;
  int rr = t >> 4, cc = (t & 15) << 2;
#pragma unroll
  for (int i = 0; i < 4; ++i) {
    int r = rr + (i << 4);
    float4 v = *(const float4*)(W + (size_t)(kb + r) * N + nb + cc);
    tile[r][cc] = v.x; tile[r][cc + 1] = v.y; tile[r][cc + 2] = v.z; tile[r][cc + 3] = v.w;
  }
  __syncthreads();
#pragma unroll
  for (int i = 0; i < 4; ++i) {
    int n = rr + (i << 4);
    ushort4 o;
    o.x = f2bf(tile[cc + 0][n]); o.y = f2bf(tile[cc + 1][n]);
    o.z = f2bf(tile[cc + 2][n]); o.w = f2bf(tile[cc + 3][n]);
    *(ushort4*)(WT + (size_t)(nb + n) * K + kb + cc) = o;
  }
}

// ---------------- LayerNorm -> hi/lo bf16 planes ---------------------------
__global__ __launch_bounds__(256) void ln_kernel(const float* __restrict__ X,
                                                 const float* __restrict__ g,
                                                 const float* __restrict__ b,
                                                 unsigned short* __restrict__ Yh,
                                                 unsigned short* __restrict__ Yl) {
  int tok = blockIdx.x;
  int t = threadIdx.x;
  const float4* xr = (const float4*)(X + (size_t)tok * D_MODEL);
  float4 v = xr[t];
  float s  = v.x + v.y + v.z + v.w;
  float s2 = v.x * v.x + v.y * v.y + v.z * v.z + v.w * v.w;
#pragma unroll
  for (int o = 32; o > 0; o >>= 1) {
    s  += __shfl_down(s, o);
    s2 += __shfl_down(s2, o);
  }
  __shared__ float red[8];
  __shared__ float mu_s, rs_s;
  int wid = t >> 6;
  if ((t & 63) == 0) { red[wid] = s; red[wid + 4] = s2; }
  __syncthreads();
  if (t == 0) {
    float ts  = red[0] + red[1] + red[2] + red[3];
    float ts2 = red[4] + red[5] + red[6] + red[7];
    float mu  = ts * (1.f / D_MODEL);
    float var = ts2 * (1.f / D_MODEL) - mu * mu;
    mu_s = mu;
    rs_s = rsqrtf(var + 1e-5f);
  }
  __syncthreads();
  float mu = mu_s, rs = rs_s;
  float4 gv = ((const float4*)g)[t];
  float4 bv = ((const float4*)b)[t];
  float o0 = (v.x - mu) * rs * gv.x + bv.x;
  float o1 = (v.y - mu) * rs * gv.y + bv.y;
  float o2 = (v.z - mu) * rs * gv.z + bv.z;
  float o3 = (v.w - mu) * rs * gv.w + bv.w;
  ushort4 hv, lv;
  hv.x = f2bf(o0); lv.x = f2bf(o0 - bf2f(hv.x));
  hv.y = f2bf(o1); lv.y = f2bf(o1 - bf2f(hv.y));
  hv.z = f2bf(o2); lv.z = f2bf(o2 - bf2f(hv.z));
  hv.w = f2bf(o3); lv.w = f2bf(o3 - bf2f(hv.w));
  ((ushort4*)(Yh + (size_t)tok * D_MODEL))[t] = hv;
  ((ushort4*)(Yl + (size_t)tok * D_MODEL))[t] = lv;
}

// ---------------- MFMA GEMM: C[M,N] = (Ah+Al)[M,K] @ BT[N,K]^T -------------
// EP: 0 fp32 | 1 phi fp32 | 2 +R fp32 | 3 gelu-LUT bf16
template <int EP, bool SPLIT>
__global__ __launch_bounds__(256, 2) void mfma_gemm(
    const unsigned short* __restrict__ Ah,
    const unsigned short* __restrict__ Al,
    const unsigned short* __restrict__ BT,
    void* Cv, const float* R, int N, int K) {
  __shared__ unsigned short smem[(SPLIT ? 3 : 2) * 8192];
  unsigned short* sAh = smem;
  unsigned short* sAl = SPLIT ? (smem + 8192) : smem;
  unsigned short* sB  = smem + (SPLIT ? 2 : 1) * 8192;

  int t = threadIdx.x;
  int w = t >> 6, l = t & 63;
  int rl = l >> 3, cl = l & 7;
  int gseg = (cl ^ rl) << 4;        // swizzled 16B segment (bytes)
  int m0 = blockIdx.y << 7;
  int n0 = blockIdx.x << 7;
  size_t strideB = (size_t)K * 2;   // row bytes for A and BT

  const char* gA[4]; const char* gAl[4]; const char* gB[4];
  int ldsOff[4];
  for (int j = 0; j < 4; ++j) {
    int row = (w << 5) + (j << 3) + rl;
    gA[j] = (const char*)Ah + (size_t)(m0 + row) * strideB + gseg;
    if (SPLIT) gAl[j] = (const char*)Al + (size_t)(m0 + row) * strideB + gseg;
    gB[j] = (const char*)BT + (size_t)(n0 + row) * strideB + gseg;
    ldsOff[j] = ((w << 5) + (j << 3)) << 6;  // row0 * 64 shorts
  }

  int wm = w >> 1, wn = w & 1;
  int m16 = l & 15, qd = l >> 4;

  f32x4 acc[4][4];
#pragma unroll
  for (int i = 0; i < 4; ++i)
#pragma unroll
    for (int j = 0; j < 4; ++j) acc[i][j] = (f32x4){0.f, 0.f, 0.f, 0.f};

  for (int k0 = 0; k0 < K; k0 += 64) {
    size_t kb = (size_t)k0 * 2;
#pragma unroll
    for (int j = 0; j < 4; ++j) {
      gl_lds16(gA[j] + kb, sAh + ldsOff[j]);
      if (SPLIT) gl_lds16(gAl[j] + kb, sAl + ldsOff[j]);
      gl_lds16(gB[j] + kb, sB + ldsOff[j]);
    }
    __syncthreads();
#pragma unroll
    for (int kk = 0; kk < 2; ++kk) {
      int ksb = (kk << 2) + qd;
      short8 afh[4], afl[4], bfr[4];
#pragma unroll
      for (int mt = 0; mt < 4; ++mt) {
        int r = (wm << 6) + (mt << 4) + m16;
        int slot = ksb ^ (r & 7);
        afh[mt] = *(const short8*)(sAh + (r << 6) + (slot << 3));
        if (SPLIT) afl[mt] = *(const short8*)(sAl + (r << 6) + (slot << 3));
      }
#pragma unroll
      for (int nt = 0; nt < 4; ++nt) {
        int r = (wn << 6) + (nt << 4) + m16;
        int slot = ksb ^ (r & 7);
        bfr[nt] = *(const short8*)(sB + (r << 6) + (slot << 3));
      }
#pragma unroll
      for (int mt = 0; mt < 4; ++mt)
#pragma unroll
        for (int nt = 0; nt < 4; ++nt) {
          acc[mt][nt] = __builtin_amdgcn_mfma_f32_16x16x32_bf16(afh[mt], bfr[nt], acc[mt][nt], 0, 0, 0);
          if (SPLIT)
            acc[mt][nt] = __builtin_amdgcn_mfma_f32_16x16x32_bf16(afl[mt], bfr[nt], acc[mt][nt], 0, 0, 0);
        }
    }
    __syncthreads();
  }

  int colBase = n0 + (wn << 6) + m16;
#pragma unroll
  for (int mt = 0; mt < 4; ++mt) {
    int rBase = m0 + (wm << 6) + (mt << 4) + (qd << 2);
#pragma unroll
    for (int nt = 0; nt < 4; ++nt) {
      int col = colBase + (nt << 4);
#pragma unroll
      for (int i = 0; i < 4; ++i) {
        size_t idx = (size_t)(rBase + i) * N + col;
        float v = acc[mt][nt][i];
        if (EP == 1)      ((float*)Cv)[idx] = phi_act(v);
        else if (EP == 2) ((float*)Cv)[idx] = R[idx] + v;
        else if (EP == 3) ((unsigned short*)Cv)[idx] = f2bf(gelu_lut(v));
        else              ((float*)Cv)[idx] = v;
      }
    }
  }
}

// ---------------- stage 1: partial kv/z over an S-chunk --------------------
// grid (KVCH, 64): blockIdx.x = chunk, blockIdx.y = bh
// P[(c*64+bh)*PSTRIDE + d*64+e] = sum_{s in chunk} phik[s,d]*v[s,e]
// P[... + 4096 + d]             = sum_{s in chunk} phik[s,d]
__global__ __launch_bounds__(256) void kvz_partial(const float* __restrict__ PK,
                                                   const float* __restrict__ V,
                                                   float* __restrict__ P) {
  int c = blockIdx.x, bh = blockIdx.y;
  int b = bh >> 4, h = bh & 15;
  __shared__ float pk[8][64];
  __shared__ float vv[8][64];
  int t = threadIdx.x;
  const size_t base = ((size_t)b * SEQ + (size_t)c * CHROWS) * D_MODEL + h * DH;
  int u = t & 127;
  int lrow = u >> 4;
  int lcol = (u & 15) << 2;
  bool isV = (t >= 128);
  const float* src = isV ? V : PK;
  int dkb = (t >> 4) << 2;
  int deb = (t & 15) << 2;
  float acc[4][4] = {};
  float zacc = 0.f;
  for (int s0 = 0; s0 < CHROWS; s0 += 8) {
    float4 ld = *(const float4*)(src + base + (size_t)(s0 + lrow) * D_MODEL + lcol);
    __syncthreads();
    if (isV) *(float4*)&vv[lrow][lcol] = ld;
    else     *(float4*)&pk[lrow][lcol] = ld;
    __syncthreads();
#pragma unroll
    for (int ss = 0; ss < 8; ++ss) {
      float4 a  = *(const float4*)&pk[ss][dkb];
      float4 bb = *(const float4*)&vv[ss][deb];
      acc[0][0] += a.x * bb.x; acc[0][1] += a.x * bb.y; acc[0][2] += a.x * bb.z; acc[0][3] += a.x * bb.w;
      acc[1][0] += a.y * bb.x; acc[1][1] += a.y * bb.y; acc[1][2] += a.y * bb.z; acc[1][3] += a.y * bb.w;
      acc[2][0] += a.z * bb.x; acc[2][1] += a.z * bb.y; acc[2][2] += a.z * bb.z; acc[2][3] += a.z * bb.w;
      acc[3][0] += a.w * bb.x; acc[3][1] += a.w * bb.y; acc[3][2] += a.w * bb.z; acc[3][3] += a.w * bb.w;
    }
    if (t < 64) {
#pragma unroll
      for (int ss = 0; ss < 8; ++ss) zacc += pk[ss][t];
    }
  }
  float* Pb = P + ((size_t)c * 64 + bh) * PSTRIDE;
#pragma unroll
  for (int i = 0; i < 4; ++i) {
    float4 o; o.x = acc[i][0]; o.y = acc[i][1]; o.z = acc[i][2]; o.w = acc[i][3];
    *(float4*)(Pb + (size_t)(dkb + i) * DH + deb) = o;
  }
  if (t < 64) Pb[4096 + t] = zacc;
}

// ---------------- stage 2: reduce partials over chunks ---------------------
// grid 64 (bh); thread loop over 4160 outputs.
__global__ __launch_bounds__(256) void kvz_reduce(const float* __restrict__ P,
                                                  float* __restrict__ KV,
                                                  float* __restrict__ Z) {
  int bh = blockIdx.x;
  int t = threadIdx.x;
  for (int i = t; i < PSTRIDE; i += 256) {
    float s = 0.f;
#pragma unroll
    for (int c = 0; c < KVCH; ++c)
      s += P[((size_t)c * 64 + bh) * PSTRIDE + i];
    if (i < 4096) KV[(size_t)bh * 4096 + i] = s;
    else          Z[(size_t)bh * 64 + (i - 4096)] = s;
  }
}

// ---------------- attn -> hi/lo bf16 planes --------------------------------
__global__ __launch_bounds__(256) void attn_kernel(const float* __restrict__ PQ,
                                                   const float* __restrict__ KVm,
                                                   const float* __restrict__ Z,
                                                   unsigned short* __restrict__ Oh,
                                                   unsigned short* __restrict__ Ol) {
  int s0 = blockIdx.x << 6;
  int h = blockIdx.y, b = blockIdx.z;
  __shared__ float Pqt[64][64];
  __shared__ float Kv[64][64];
  __shared__ float den[64];
  __shared__ float zsh[64];
  int t = threadIdx.x;
  size_t qbase  = ((size_t)b * SEQ + s0) * D_MODEL + h * DH;
  size_t kvbase = (size_t)(b * NHEADS + h) * (DH * DH);
  int r0 = t >> 4;
  int c4 = (t & 15) << 2;
#pragma unroll
  for (int rr = 0; rr < 4; ++rr) {
    int row = r0 + (rr << 4);
    *(float4*)&Kv[row][c4] = *(const float4*)(KVm + kvbase + (size_t)row * DH + c4);
    float4 q = *(const float4*)(PQ + qbase + (size_t)row * D_MODEL + c4);
    Pqt[c4 + 0][row] = q.x;
    Pqt[c4 + 1][row] = q.y;
    Pqt[c4 + 2][row] = q.z;
    Pqt[c4 + 3][row] = q.w;
  }
  if (t < 16) *(float4*)&zsh[t << 2] = *(const float4*)(Z + (size_t)(b * NHEADS + h) * DH + (t << 2));
  __syncthreads();
  if (t < 64) {
    float d_ = 1e-6f;
#pragma unroll
    for (int dd = 0; dd < 64; ++dd) d_ += Pqt[dd][t] * zsh[dd];
    den[t] = d_;
  }
  __syncthreads();
  int tokb = (t >> 4) << 2, eb = (t & 15) << 2;
  float acc[4][4] = {};
#pragma unroll 8
  for (int dd = 0; dd < 64; ++dd) {
    float4 a  = *(const float4*)&Pqt[dd][tokb];
    float4 bb = *(const float4*)&Kv[dd][eb];
    acc[0][0] += a.x * bb.x; acc[0][1] += a.x * bb.y; acc[0][2] += a.x * bb.z; acc[0][3] += a.x * bb.w;
    acc[1][0] += a.y * bb.x; acc[1][1] += a.y * bb.y; acc[1][2] += a.y * bb.z; acc[1][3] += a.y * bb.w;
    acc[2][0] += a.z * bb.x; acc[2][1] += a.z * bb.y; acc[2][2] += a.z * bb.z; acc[2][3] += a.z * bb.w;
    acc[3][0] += a.w * bb.x; acc[3][1] += a.w * bb.y; acc[3][2] += a.w * bb.z; acc[3][3] += a.w * bb.w;
  }
#pragma unroll
  for (int i = 0; i < 4; ++i) {
    float dv = den[tokb + i];
    float v0 = acc[i][0] / dv, v1 = acc[i][1] / dv, v2 = acc[i][2] / dv, v3 = acc[i][3] / dv;
    ushort4 hv, lv;
    hv.x = f2bf(v0); lv.x = f2bf(v0 - bf2f(hv.x));
    hv.y = f2bf(v1); lv.y = f2bf(v1 - bf2f(hv.y));
    hv.z = f2bf(v2); lv.z = f2bf(v2 - bf2f(hv.z));
    hv.w = f2bf(v3); lv.w = f2bf(v3 - bf2f(hv.w));
    size_t oidx = ((size_t)b * SEQ + s0 + tokb + i) * D_MODEL + h * DH + eb;
    *(ushort4*)(Oh + oidx) = hv;
    *(ushort4*)(Ol + oidx) = lv;
  }
}

extern "C" void kernel_launch(void* const* d_in, const int* in_sizes, int n_in,
                              void* d_out, int out_size, void* d_ws, size_t ws_size,
                              hipStream_t stream) {
  const float* x    = (const float*)d_in[0];
  const float* ln1g = (const float*)d_in[1];
  const float* ln1b = (const float*)d_in[2];
  const float* wq   = (const float*)d_in[3];
  const float* wk   = (const float*)d_in[4];
  const float* wv   = (const float*)d_in[5];
  const float* wo   = (const float*)d_in[6];
  const float* ln2g = (const float*)d_in[7];
  const float* ln2b = (const float*)d_in[8];
  const float* w1   = (const float*)d_in[9];
  const float* w2   = (const float*)d_in[10];
  float* out = (float*)d_out;
  char* ws = (char*)d_ws;

  const size_t MB = 1024 * 1024;
  unsigned short* xnh  = (unsigned short*)(ws);
  unsigned short* xnl  = (unsigned short*)(ws + 16 * MB);
  float*          phiq = (float*)(ws + 32 * MB);
  float*          phik = (float*)(ws + 64 * MB);
  float*          vbuf = (float*)(ws + 96 * MB);
  unsigned short* ffn  = (unsigned short*)(ws + 32 * MB);   // overlays phiq+phik
  unsigned short* w1T  = (unsigned short*)(ws + 96 * MB);   // overlays vbuf
  unsigned short* w2T  = (unsigned short*)(ws + 104 * MB);
  unsigned short* woT  = (unsigned short*)(ws + 128 * MB);

  // d_out as scratch until wo-GEMM writes it
  unsigned short* wqT = (unsigned short*)d_out;
  unsigned short* wkT = wqT + (size_t)D_MODEL * D_MODEL;
  unsigned short* wvT = wkT + (size_t)D_MODEL * D_MODEL;
  float* kvP = (float*)((char*)d_out + 6 * MB);             // 16*64*4160 floats (17.04MB)
  float* kv  = (float*)((char*)d_out + 24 * MB);            // 64*4096 floats
  float* z   = (float*)((char*)d_out + 25 * MB);            // 4096 floats

  dim3 blk(256);
  dim3 gcD(D_MODEL / 64, D_MODEL / 64);

  // weight convert+transpose (wq/wk/wv/wo now; w1/w2 later, after vbuf dies)
  convT<<<gcD, blk, 0, stream>>>(wq, wqT, D_MODEL, D_MODEL);
  convT<<<gcD, blk, 0, stream>>>(wk, wkT, D_MODEL, D_MODEL);
  convT<<<gcD, blk, 0, stream>>>(wv, wvT, D_MODEL, D_MODEL);
  convT<<<gcD, blk, 0, stream>>>(wo, woT, D_MODEL, D_MODEL);

  // LN1 -> hi/lo
  ln_kernel<<<NTOK, blk, 0, stream>>>(x, ln1g, ln1b, xnh, xnl);

  dim3 gD(D_MODEL / 128, NTOK / 128);
  // q,k,v projections
  mfma_gemm<1, true><<<gD, blk, 0, stream>>>(xnh, xnl, wqT, phiq, nullptr, D_MODEL, D_MODEL);
  mfma_gemm<1, true><<<gD, blk, 0, stream>>>(xnh, xnl, wkT, phik, nullptr, D_MODEL, D_MODEL);
  mfma_gemm<0, true><<<gD, blk, 0, stream>>>(xnh, xnl, wvT, vbuf, nullptr, D_MODEL, D_MODEL);

  // kv, z: two-stage S-split reduction
  kvz_partial<<<dim3(KVCH, BATCH * NHEADS), blk, 0, stream>>>(phik, vbuf, kvP);
  kvz_reduce<<<BATCH * NHEADS, blk, 0, stream>>>(kvP, kv, z);

  // attn -> hi/lo planes (reuse xn slots; xn is dead until LN2)
  attn_kernel<<<dim3(SEQ / 64, NHEADS, BATCH), blk, 0, stream>>>(phiq, kv, z, xnh, xnl);

  // w1T/w2T conversions into vbuf region (dead after kvz)
  convT<<<dim3(DFF / 64, D_MODEL / 64), blk, 0, stream>>>(w1, w1T, D_MODEL, DFF);
  convT<<<dim3(D_MODEL / 64, DFF / 64), blk, 0, stream>>>(w2, w2T, DFF, D_MODEL);

  // x1 = x + attn@wo -> out (kv/z scratch in out dead by stream order)
  mfma_gemm<2, true><<<gD, blk, 0, stream>>>(xnh, xnl, woT, out, x, D_MODEL, D_MODEL);

  // LN2 -> hi/lo
  ln_kernel<<<NTOK, blk, 0, stream>>>(out, ln2g, ln2b, xnh, xnl);

  // ffn = gelu_lut(h @ w1) -> bf16
  dim3 gF(DFF / 128, NTOK / 128);
  mfma_gemm<3, true><<<gF, blk, 0, stream>>>(xnh, xnl, w1T, ffn, nullptr, DFF, D_MODEL);

  // out += ffn @ w2 (single-plane bf16 A)
  mfma_gemm<2, false><<<gD, blk, 0, stream>>>(ffn, nullptr, w2T, out, out, D_MODEL, DFF);
}

// Round 5
// 510.722 us; speedup vs baseline: 6.5966x; 1.2745x over previous
//
#include <hip/hip_runtime.h>
#include <cstdint>
#include <cstddef>

// PiFormerBlock, MFMA fp16 single-plane version (round 5).
//   x = x + linattn(LN1(x)) @ wo ;  x = x + gelu_lut(LN2(x) @ w1) @ w2
// GEMMs: 128x128 tile, BK=64, mfma_f32_16x16x32_f16, global_load_lds(16B),
// XOR-swizzled LDS. Weights are ternary powers of two -> EXACT in fp16;
// activations carried as single fp16 plane (2^-11 rel err; bf16's 2^-8 was
// unsafe through the 0.1-wide GELU-LUT bins, hence round-4's hi/lo split.
// fp16 halves MFMA work vs split-bf16 at the same matrix rate).
//
// ws layout (bytes):
//   0        xn     [8192x1024] fp16 (16MB)   (reused as attn out)
//   16MB     (free)
//   32MB     phiq   fp32 (32MB)  \__ later overlaid by ffn fp16 (64MB)
//   64MB     phik   fp32 (32MB)  /
//   96MB     vbuf   fp32 (32MB)  -- later overlaid by w1T (8MB) + w2T (8MB)
//   128MB    woT    fp16 (2MB)
// d_out scratch (dead before wo-GEMM writes it):
//   0MB wqT/wkT/wvT (6MB) | 6MB kv partials (17.04MB) | 24MB kv (1MB) | 25MB z

#define D_MODEL 1024
#define SEQ     2048
#define BATCH   4
#define NTOK    8192
#define NHEADS  16
#define DH      64
#define DFF     4096
#define KVCH    16
#define CHROWS  (SEQ / KVCH)
#define PSTRIDE 4160

typedef _Float16 half8 __attribute__((ext_vector_type(8)));
typedef float f32x4 __attribute__((ext_vector_type(4)));

__device__ __forceinline__ unsigned short f2h(float x) {
  _Float16 h = (_Float16)x;            // v_cvt_f16_f32, round-nearest-even
  union { _Float16 h; unsigned short u; } c; c.h = h; return c.u;
}

__device__ __forceinline__ float phi_act(float x) {
  return x > 0.f ? x + 1.f : expf(x);
}

__device__ __forceinline__ float gelu_lut(float x) {
  float r = rintf(x / 0.1f);
  r = fminf(fmaxf(r, -128.f), 127.f);
  float v = r * 0.1f;
  float c = 0.7978845608028654f;
  float t = tanhf(c * (v + 0.044715f * v * v * v));
  return 0.5f * v * (1.f + t);
}

__device__ __forceinline__ void gl_lds16(const void* g, void* l) {
  __builtin_amdgcn_global_load_lds(
      (const __attribute__((address_space(1))) unsigned int*)g,
      (__attribute__((address_space(3))) unsigned int*)l, 16, 0, 0);
}

// ---------------- transpose-convert: W fp32 [K,N] -> WT fp16 [N,K] ----------
__global__ __launch_bounds__(256) void convT(const float* __restrict__ W,
                                             unsigned short* __restrict__ WT,
                                             int K, int N) {
  __shared__ float tile[64][65];
  int kb = blockIdx.y << 6, nb = blockIdx.x << 6;
  int t = threadIdx.x;
  int rr = t >> 4, cc = (t & 15) << 2;
#pragma unroll
  for (int i = 0; i < 4; ++i) {
    int r = rr + (i << 4);
    float4 v = *(const float4*)(W + (size_t)(kb + r) * N + nb + cc);
    tile[r][cc] = v.x; tile[r][cc + 1] = v.y; tile[r][cc + 2] = v.z; tile[r][cc + 3] = v.w;
  }
  __syncthreads();
#pragma unroll
  for (int i = 0; i < 4; ++i) {
    int n = rr + (i << 4);
    ushort4 o;
    o.x = f2h(tile[cc + 0][n]); o.y = f2h(tile[cc + 1][n]);
    o.z = f2h(tile[cc + 2][n]); o.w = f2h(tile[cc + 3][n]);
    *(ushort4*)(WT + (size_t)(nb + n) * K + kb + cc) = o;
  }
}

// ---------------- LayerNorm -> fp16 ----------------------------------------
__global__ __launch_bounds__(256) void ln_kernel(const float* __restrict__ X,
                                                 const float* __restrict__ g,
                                                 const float* __restrict__ b,
                                                 unsigned short* __restrict__ Y) {
  int tok = blockIdx.x;
  int t = threadIdx.x;
  const float4* xr = (const float4*)(X + (size_t)tok * D_MODEL);
  float4 v = xr[t];
  float s  = v.x + v.y + v.z + v.w;
  float s2 = v.x * v.x + v.y * v.y + v.z * v.z + v.w * v.w;
#pragma unroll
  for (int o = 32; o > 0; o >>= 1) {
    s  += __shfl_down(s, o);
    s2 += __shfl_down(s2, o);
  }
  __shared__ float red[8];
  __shared__ float mu_s, rs_s;
  int wid = t >> 6;
  if ((t & 63) == 0) { red[wid] = s; red[wid + 4] = s2; }
  __syncthreads();
  if (t == 0) {
    float ts  = red[0] + red[1] + red[2] + red[3];
    float ts2 = red[4] + red[5] + red[6] + red[7];
    float mu  = ts * (1.f / D_MODEL);
    float var = ts2 * (1.f / D_MODEL) - mu * mu;
    mu_s = mu;
    rs_s = rsqrtf(var + 1e-5f);
  }
  __syncthreads();
  float mu = mu_s, rs = rs_s;
  float4 gv = ((const float4*)g)[t];
  float4 bv = ((const float4*)b)[t];
  ushort4 hv;
  hv.x = f2h((v.x - mu) * rs * gv.x + bv.x);
  hv.y = f2h((v.y - mu) * rs * gv.y + bv.y);
  hv.z = f2h((v.z - mu) * rs * gv.z + bv.z);
  hv.w = f2h((v.w - mu) * rs * gv.w + bv.w);
  ((ushort4*)(Y + (size_t)tok * D_MODEL))[t] = hv;
}

// ---------------- MFMA GEMM: C[M,N] = A[M,K] @ BT[N,K]^T (fp16 in) ---------
// EP: 0 fp32 | 1 phi fp32 | 2 +R fp32 | 3 gelu-LUT fp16
template <int EP>
__global__ __launch_bounds__(256, 2) void mfma_gemm(
    const unsigned short* __restrict__ A,
    const unsigned short* __restrict__ BT,
    void* Cv, const float* R, int N, int K) {
  __shared__ unsigned short smem[2 * 8192];
  unsigned short* sA = smem;
  unsigned short* sB = smem + 8192;

  int t = threadIdx.x;
  int w = t >> 6, l = t & 63;
  int rl = l >> 3, cl = l & 7;
  int gseg = (cl ^ rl) << 4;        // swizzled 16B segment (bytes)
  int m0 = blockIdx.y << 7;
  int n0 = blockIdx.x << 7;
  size_t strideB = (size_t)K * 2;

  const char* gA[4]; const char* gB[4];
  int ldsOff[4];
  for (int j = 0; j < 4; ++j) {
    int row = (w << 5) + (j << 3) + rl;
    gA[j] = (const char*)A + (size_t)(m0 + row) * strideB + gseg;
    gB[j] = (const char*)BT + (size_t)(n0 + row) * strideB + gseg;
    ldsOff[j] = ((w << 5) + (j << 3)) << 6;
  }

  int wm = w >> 1, wn = w & 1;
  int m16 = l & 15, qd = l >> 4;

  f32x4 acc[4][4];
#pragma unroll
  for (int i = 0; i < 4; ++i)
#pragma unroll
    for (int j = 0; j < 4; ++j) acc[i][j] = (f32x4){0.f, 0.f, 0.f, 0.f};

  for (int k0 = 0; k0 < K; k0 += 64) {
    size_t kb = (size_t)k0 * 2;
#pragma unroll
    for (int j = 0; j < 4; ++j) {
      gl_lds16(gA[j] + kb, sA + ldsOff[j]);
      gl_lds16(gB[j] + kb, sB + ldsOff[j]);
    }
    __syncthreads();
#pragma unroll
    for (int kk = 0; kk < 2; ++kk) {
      int ksb = (kk << 2) + qd;
      half8 af[4], bf[4];
#pragma unroll
      for (int mt = 0; mt < 4; ++mt) {
        int r = (wm << 6) + (mt << 4) + m16;
        int slot = ksb ^ (r & 7);
        af[mt] = *(const half8*)(sA + (r << 6) + (slot << 3));
      }
#pragma unroll
      for (int nt = 0; nt < 4; ++nt) {
        int r = (wn << 6) + (nt << 4) + m16;
        int slot = ksb ^ (r & 7);
        bf[nt] = *(const half8*)(sB + (r << 6) + (slot << 3));
      }
#pragma unroll
      for (int mt = 0; mt < 4; ++mt)
#pragma unroll
        for (int nt = 0; nt < 4; ++nt)
          acc[mt][nt] = __builtin_amdgcn_mfma_f32_16x16x32_f16(af[mt], bf[nt], acc[mt][nt], 0, 0, 0);
    }
    __syncthreads();
  }

  int colBase = n0 + (wn << 6) + m16;
#pragma unroll
  for (int mt = 0; mt < 4; ++mt) {
    int rBase = m0 + (wm << 6) + (mt << 4) + (qd << 2);
#pragma unroll
    for (int nt = 0; nt < 4; ++nt) {
      int col = colBase + (nt << 4);
#pragma unroll
      for (int i = 0; i < 4; ++i) {
        size_t idx = (size_t)(rBase + i) * N + col;
        float v = acc[mt][nt][i];
        if (EP == 1)      ((float*)Cv)[idx] = phi_act(v);
        else if (EP == 2) ((float*)Cv)[idx] = R[idx] + v;
        else if (EP == 3) ((unsigned short*)Cv)[idx] = f2h(gelu_lut(v));
        else              ((float*)Cv)[idx] = v;
      }
    }
  }
}

// ---------------- stage 1: partial kv/z over an S-chunk --------------------
__global__ __launch_bounds__(256) void kvz_partial(const float* __restrict__ PK,
                                                   const float* __restrict__ V,
                                                   float* __restrict__ P) {
  int c = blockIdx.x, bh = blockIdx.y;
  int b = bh >> 4, h = bh & 15;
  __shared__ float pk[8][64];
  __shared__ float vv[8][64];
  int t = threadIdx.x;
  const size_t base = ((size_t)b * SEQ + (size_t)c * CHROWS) * D_MODEL + h * DH;
  int u = t & 127;
  int lrow = u >> 4;
  int lcol = (u & 15) << 2;
  bool isV = (t >= 128);
  const float* src = isV ? V : PK;
  int dkb = (t >> 4) << 2;
  int deb = (t & 15) << 2;
  float acc[4][4] = {};
  float zacc = 0.f;
  for (int s0 = 0; s0 < CHROWS; s0 += 8) {
    float4 ld = *(const float4*)(src + base + (size_t)(s0 + lrow) * D_MODEL + lcol);
    __syncthreads();
    if (isV) *(float4*)&vv[lrow][lcol] = ld;
    else     *(float4*)&pk[lrow][lcol] = ld;
    __syncthreads();
#pragma unroll
    for (int ss = 0; ss < 8; ++ss) {
      float4 a  = *(const float4*)&pk[ss][dkb];
      float4 bb = *(const float4*)&vv[ss][deb];
      acc[0][0] += a.x * bb.x; acc[0][1] += a.x * bb.y; acc[0][2] += a.x * bb.z; acc[0][3] += a.x * bb.w;
      acc[1][0] += a.y * bb.x; acc[1][1] += a.y * bb.y; acc[1][2] += a.y * bb.z; acc[1][3] += a.y * bb.w;
      acc[2][0] += a.z * bb.x; acc[2][1] += a.z * bb.y; acc[2][2] += a.z * bb.z; acc[2][3] += a.z * bb.w;
      acc[3][0] += a.w * bb.x; acc[3][1] += a.w * bb.y; acc[3][2] += a.w * bb.z; acc[3][3] += a.w * bb.w;
    }
    if (t < 64) {
#pragma unroll
      for (int ss = 0; ss < 8; ++ss) zacc += pk[ss][t];
    }
  }
  float* Pb = P + ((size_t)c * 64 + bh) * PSTRIDE;
#pragma unroll
  for (int i = 0; i < 4; ++i) {
    float4 o; o.x = acc[i][0]; o.y = acc[i][1]; o.z = acc[i][2]; o.w = acc[i][3];
    *(float4*)(Pb + (size_t)(dkb + i) * DH + deb) = o;
  }
  if (t < 64) Pb[4096 + t] = zacc;
}

// ---------------- stage 2: reduce partials over chunks ---------------------
__global__ __launch_bounds__(256) void kvz_reduce(const float* __restrict__ P,
                                                  float* __restrict__ KV,
                                                  float* __restrict__ Z) {
  int bh = blockIdx.x;
  int t = threadIdx.x;
  for (int i = t; i < PSTRIDE; i += 256) {
    float s = 0.f;
#pragma unroll
    for (int c = 0; c < KVCH; ++c)
      s += P[((size_t)c * 64 + bh) * PSTRIDE + i];
    if (i < 4096) KV[(size_t)bh * 4096 + i] = s;
    else          Z[(size_t)bh * 64 + (i - 4096)] = s;
  }
}

// ---------------- attn -> fp16 ---------------------------------------------
__global__ __launch_bounds__(256) void attn_kernel(const float* __restrict__ PQ,
                                                   const float* __restrict__ KVm,
                                                   const float* __restrict__ Z,
                                                   unsigned short* __restrict__ O) {
  int s0 = blockIdx.x << 6;
  int h = blockIdx.y, b = blockIdx.z;
  __shared__ float Pqt[64][64];
  __shared__ float Kv[64][64];
  __shared__ float den[64];
  __shared__ float zsh[64];
  int t = threadIdx.x;
  size_t qbase  = ((size_t)b * SEQ + s0) * D_MODEL + h * DH;
  size_t kvbase = (size_t)(b * NHEADS + h) * (DH * DH);
  int r0 = t >> 4;
  int c4 = (t & 15) << 2;
#pragma unroll
  for (int rr = 0; rr < 4; ++rr) {
    int row = r0 + (rr << 4);
    *(float4*)&Kv[row][c4] = *(const float4*)(KVm + kvbase + (size_t)row * DH + c4);
    float4 q = *(const float4*)(PQ + qbase + (size_t)row * D_MODEL + c4);
    Pqt[c4 + 0][row] = q.x;
    Pqt[c4 + 1][row] = q.y;
    Pqt[c4 + 2][row] = q.z;
    Pqt[c4 + 3][row] = q.w;
  }
  if (t < 16) *(float4*)&zsh[t << 2] = *(const float4*)(Z + (size_t)(b * NHEADS + h) * DH + (t << 2));
  __syncthreads();
  if (t < 64) {
    float d_ = 1e-6f;
#pragma unroll
    for (int dd = 0; dd < 64; ++dd) d_ += Pqt[dd][t] * zsh[dd];
    den[t] = d_;
  }
  __syncthreads();
  int tokb = (t >> 4) << 2, eb = (t & 15) << 2;
  float acc[4][4] = {};
#pragma unroll 8
  for (int dd = 0; dd < 64; ++dd) {
    float4 a  = *(const float4*)&Pqt[dd][tokb];
    float4 bb = *(const float4*)&Kv[dd][eb];
    acc[0][0] += a.x * bb.x; acc[0][1] += a.x * bb.y; acc[0][2] += a.x * bb.z; acc[0][3] += a.x * bb.w;
    acc[1][0] += a.y * bb.x; acc[1][1] += a.y * bb.y; acc[1][2] += a.y * bb.z; acc[1][3] += a.y * bb.w;
    acc[2][0] += a.z * bb.x; acc[2][1] += a.z * bb.y; acc[2][2] += a.z * bb.z; acc[2][3] += a.z * bb.w;
    acc[3][0] += a.w * bb.x; acc[3][1] += a.w * bb.y; acc[3][2] += a.w * bb.z; acc[3][3] += a.w * bb.w;
  }
#pragma unroll
  for (int i = 0; i < 4; ++i) {
    float dv = den[tokb + i];
    ushort4 hv;
    hv.x = f2h(acc[i][0] / dv);
    hv.y = f2h(acc[i][1] / dv);
    hv.z = f2h(acc[i][2] / dv);
    hv.w = f2h(acc[i][3] / dv);
    size_t oidx = ((size_t)b * SEQ + s0 + tokb + i) * D_MODEL + h * DH + eb;
    *(ushort4*)(O + oidx) = hv;
  }
}

extern "C" void kernel_launch(void* const* d_in, const int* in_sizes, int n_in,
                              void* d_out, int out_size, void* d_ws, size_t ws_size,
                              hipStream_t stream) {
  const float* x    = (const float*)d_in[0];
  const float* ln1g = (const float*)d_in[1];
  const float* ln1b = (const float*)d_in[2];
  const float* wq   = (const float*)d_in[3];
  const float* wk   = (const float*)d_in[4];
  const float* wv   = (const float*)d_in[5];
  const float* wo   = (const float*)d_in[6];
  const float* ln2g = (const float*)d_in[7];
  const float* ln2b = (const float*)d_in[8];
  const float* w1   = (const float*)d_in[9];
  const float* w2   = (const float*)d_in[10];
  float* out = (float*)d_out;
  char* ws = (char*)d_ws;

  const size_t MB = 1024 * 1024;
  unsigned short* xn   = (unsigned short*)(ws);
  float*          phiq = (float*)(ws + 32 * MB);
  float*          phik = (float*)(ws + 64 * MB);
  float*          vbuf = (float*)(ws + 96 * MB);
  unsigned short* ffn  = (unsigned short*)(ws + 32 * MB);   // overlays phiq+phik
  unsigned short* w1T  = (unsigned short*)(ws + 96 * MB);   // overlays vbuf
  unsigned short* w2T  = (unsigned short*)(ws + 104 * MB);
  unsigned short* woT  = (unsigned short*)(ws + 128 * MB);

  // d_out as scratch until wo-GEMM writes it
  unsigned short* wqT = (unsigned short*)d_out;
  unsigned short* wkT = wqT + (size_t)D_MODEL * D_MODEL;
  unsigned short* wvT = wkT + (size_t)D_MODEL * D_MODEL;
  float* kvP = (float*)((char*)d_out + 6 * MB);
  float* kv  = (float*)((char*)d_out + 24 * MB);
  float* z   = (float*)((char*)d_out + 25 * MB);

  dim3 blk(256);
  dim3 gcD(D_MODEL / 64, D_MODEL / 64);

  convT<<<gcD, blk, 0, stream>>>(wq, wqT, D_MODEL, D_MODEL);
  convT<<<gcD, blk, 0, stream>>>(wk, wkT, D_MODEL, D_MODEL);
  convT<<<gcD, blk, 0, stream>>>(wv, wvT, D_MODEL, D_MODEL);
  convT<<<gcD, blk, 0, stream>>>(wo, woT, D_MODEL, D_MODEL);

  ln_kernel<<<NTOK, blk, 0, stream>>>(x, ln1g, ln1b, xn);

  dim3 gD(D_MODEL / 128, NTOK / 128);
  mfma_gemm<1><<<gD, blk, 0, stream>>>(xn, wqT, phiq, nullptr, D_MODEL, D_MODEL);
  mfma_gemm<1><<<gD, blk, 0, stream>>>(xn, wkT, phik, nullptr, D_MODEL, D_MODEL);
  mfma_gemm<0><<<gD, blk, 0, stream>>>(xn, wvT, vbuf, nullptr, D_MODEL, D_MODEL);

  kvz_partial<<<dim3(KVCH, BATCH * NHEADS), blk, 0, stream>>>(phik, vbuf, kvP);
  kvz_reduce<<<BATCH * NHEADS, blk, 0, stream>>>(kvP, kv, z);

  // attn -> fp16 (reuse xn slot; xn dead until LN2)
  attn_kernel<<<dim3(SEQ / 64, NHEADS, BATCH), blk, 0, stream>>>(phiq, kv, z, xn);

  convT<<<dim3(DFF / 64, D_MODEL / 64), blk, 0, stream>>>(w1, w1T, D_MODEL, DFF);
  convT<<<dim3(D_MODEL / 64, DFF / 64), blk, 0, stream>>>(w2, w2T, DFF, D_MODEL);

  // x1 = x + attn@wo -> out
  mfma_gemm<2><<<gD, blk, 0, stream>>>(xn, woT, out, x, D_MODEL, D_MODEL);

  // LN2 -> fp16
  ln_kernel<<<NTOK, blk, 0, stream>>>(out, ln2g, ln2b, xn);

  // ffn = gelu_lut(h @ w1) -> fp16
  dim3 gF(DFF / 128, NTOK / 128);
  mfma_gemm<3><<<gF, blk, 0, stream>>>(xn, w1T, ffn, nullptr, DFF, D_MODEL);

  // out += ffn @ w2
  mfma_gemm<2><<<gD, blk, 0, stream>>>(ffn, w2T, out, out, D_MODEL, DFF);
}

// Round 6
// 496.865 us; speedup vs baseline: 6.7806x; 1.0279x over previous
//
#include <hip/hip_runtime.h>
#include <cstdint>
#include <cstddef>

// PiFormerBlock, MFMA fp16 version, round 6.
//   x = x + linattn(LN1(x)) @ wo ;  x = x + gelu_lut(LN2(x) @ w1) @ w2
// Round-6 changes (all inside mfma_gemm):
//  - XCD-aware block swizzle: linear block id L, xcd=L&7; each XCD owns a
//    contiguous band of gridDim.y/8 m-rows, walks n fastest -> A-tile stays in
//    that XCD's private L2 for all its n-consumers (w2 fetch was 2.8x ideal).
//  - EP=3 epilogue uses a 256-entry GELU table built in LDS (256 tanhf per
//    block) instead of per-element tanhf (w1 VALUBusy was 68%).
//  - __launch_bounds__(256,4): occupancy toward the 32KB-LDS limit.
//
// ws layout (bytes):
//   0        xn     [8192x1024] fp16 (16MB)   (reused as attn out)
//   32MB     phiq   fp32 (32MB)  \__ later overlaid by ffn fp16 (64MB)
//   64MB     phik   fp32 (32MB)  /
//   96MB     vbuf   fp32 (32MB)  -- later overlaid by w1T (8MB) + w2T (8MB)
//   128MB    woT    fp16 (2MB)
// d_out scratch (dead before wo-GEMM writes it):
//   0MB wqT/wkT/wvT (6MB) | 6MB kv partials (17.04MB) | 24MB kv (1MB) | 25MB z

#define D_MODEL 1024
#define SEQ     2048
#define BATCH   4
#define NTOK    8192
#define NHEADS  16
#define DH      64
#define DFF     4096
#define KVCH    16
#define CHROWS  (SEQ / KVCH)
#define PSTRIDE 4160

typedef _Float16 half8 __attribute__((ext_vector_type(8)));
typedef float f32x4 __attribute__((ext_vector_type(4)));

__device__ __forceinline__ unsigned short f2h(float x) {
  _Float16 h = (_Float16)x;
  union { _Float16 h; unsigned short u; } c; c.h = h; return c.u;
}

__device__ __forceinline__ float phi_act(float x) {
  return x > 0.f ? x + 1.f : expf(x);
}

__device__ __forceinline__ float gelu_exact(float v) {
  float c = 0.7978845608028654f;
  float t = tanhf(c * (v + 0.044715f * v * v * v));
  return 0.5f * v * (1.f + t);
}

__device__ __forceinline__ void gl_lds16(const void* g, void* l) {
  __builtin_amdgcn_global_load_lds(
      (const __attribute__((address_space(1))) unsigned int*)g,
      (__attribute__((address_space(3))) unsigned int*)l, 16, 0, 0);
}

// ---------------- transpose-convert: W fp32 [K,N] -> WT fp16 [N,K] ----------
__global__ __launch_bounds__(256) void convT(const float* __restrict__ W,
                                             unsigned short* __restrict__ WT,
                                             int K, int N) {
  __shared__ float tile[64][65];
  int kb = blockIdx.y << 6, nb = blockIdx.x << 6;
  int t = threadIdx.x;
  int rr = t >> 4, cc = (t & 15) << 2;
#pragma unroll
  for (int i = 0; i < 4; ++i) {
    int r = rr + (i << 4);
    float4 v = *(const float4*)(W + (size_t)(kb + r) * N + nb + cc);
    tile[r][cc] = v.x; tile[r][cc + 1] = v.y; tile[r][cc + 2] = v.z; tile[r][cc + 3] = v.w;
  }
  __syncthreads();
#pragma unroll
  for (int i = 0; i < 4; ++i) {
    int n = rr + (i << 4);
    ushort4 o;
    o.x = f2h(tile[cc + 0][n]); o.y = f2h(tile[cc + 1][n]);
    o.z = f2h(tile[cc + 2][n]); o.w = f2h(tile[cc + 3][n]);
    *(ushort4*)(WT + (size_t)(nb + n) * K + kb + cc) = o;
  }
}

// ---------------- LayerNorm -> fp16 ----------------------------------------
__global__ __launch_bounds__(256) void ln_kernel(const float* __restrict__ X,
                                                 const float* __restrict__ g,
                                                 const float* __restrict__ b,
                                                 unsigned short* __restrict__ Y) {
  int tok = blockIdx.x;
  int t = threadIdx.x;
  const float4* xr = (const float4*)(X + (size_t)tok * D_MODEL);
  float4 v = xr[t];
  float s  = v.x + v.y + v.z + v.w;
  float s2 = v.x * v.x + v.y * v.y + v.z * v.z + v.w * v.w;
#pragma unroll
  for (int o = 32; o > 0; o >>= 1) {
    s  += __shfl_down(s, o);
    s2 += __shfl_down(s2, o);
  }
  __shared__ float red[8];
  __shared__ float mu_s, rs_s;
  int wid = t >> 6;
  if ((t & 63) == 0) { red[wid] = s; red[wid + 4] = s2; }
  __syncthreads();
  if (t == 0) {
    float ts  = red[0] + red[1] + red[2] + red[3];
    float ts2 = red[4] + red[5] + red[6] + red[7];
    float mu  = ts * (1.f / D_MODEL);
    float var = ts2 * (1.f / D_MODEL) - mu * mu;
    mu_s = mu;
    rs_s = rsqrtf(var + 1e-5f);
  }
  __syncthreads();
  float mu = mu_s, rs = rs_s;
  float4 gv = ((const float4*)g)[t];
  float4 bv = ((const float4*)b)[t];
  ushort4 hv;
  hv.x = f2h((v.x - mu) * rs * gv.x + bv.x);
  hv.y = f2h((v.y - mu) * rs * gv.y + bv.y);
  hv.z = f2h((v.z - mu) * rs * gv.z + bv.z);
  hv.w = f2h((v.w - mu) * rs * gv.w + bv.w);
  ((ushort4*)(Y + (size_t)tok * D_MODEL))[t] = hv;
}

// ---------------- MFMA GEMM: C[M,N] = A[M,K] @ BT[N,K]^T (fp16 in) ---------
// EP: 0 fp32 | 1 phi fp32 | 2 +R fp32 | 3 gelu-LUT fp16
template <int EP>
__global__ __launch_bounds__(256, 4) void mfma_gemm(
    const unsigned short* __restrict__ A,
    const unsigned short* __restrict__ BT,
    void* Cv, const float* R, int N, int K) {
  __shared__ unsigned short smem[2 * 8192];
  __shared__ float gtab[EP == 3 ? 256 : 1];
  unsigned short* sA = smem;
  unsigned short* sB = smem + 8192;

  int t = threadIdx.x;
  if (EP == 3) gtab[t & 255] = gelu_exact((float)((t & 255) - 128) * 0.1f);

  // XCD-aware swizzle (8 XCDs, round-robin on linear block id).
  int bm, bn;
  {
    int L = blockIdx.y * gridDim.x + blockIdx.x;
    if ((gridDim.y & 7) == 0) {
      int xcd = L & 7, wi = L >> 3;
      int mPerX = gridDim.y >> 3;
      bm = xcd * mPerX + wi / gridDim.x;   // m band local to this XCD
      bn = wi % gridDim.x;                 // n fastest -> A-tile L2 reuse
    } else {
      bn = blockIdx.x; bm = blockIdx.y;
    }
  }

  int w = t >> 6, l = t & 63;
  int rl = l >> 3, cl = l & 7;
  int gseg = (cl ^ rl) << 4;        // swizzled 16B segment (bytes)
  int m0 = bm << 7;
  int n0 = bn << 7;
  size_t strideB = (size_t)K * 2;

  const char* gA[4]; const char* gB[4];
  int ldsOff[4];
  for (int j = 0; j < 4; ++j) {
    int row = (w << 5) + (j << 3) + rl;
    gA[j] = (const char*)A + (size_t)(m0 + row) * strideB + gseg;
    gB[j] = (const char*)BT + (size_t)(n0 + row) * strideB + gseg;
    ldsOff[j] = ((w << 5) + (j << 3)) << 6;
  }

  int wm = w >> 1, wn = w & 1;
  int m16 = l & 15, qd = l >> 4;

  f32x4 acc[4][4];
#pragma unroll
  for (int i = 0; i < 4; ++i)
#pragma unroll
    for (int j = 0; j < 4; ++j) acc[i][j] = (f32x4){0.f, 0.f, 0.f, 0.f};

  for (int k0 = 0; k0 < K; k0 += 64) {
    size_t kb = (size_t)k0 * 2;
#pragma unroll
    for (int j = 0; j < 4; ++j) {
      gl_lds16(gA[j] + kb, sA + ldsOff[j]);
      gl_lds16(gB[j] + kb, sB + ldsOff[j]);
    }
    __syncthreads();
#pragma unroll
    for (int kk = 0; kk < 2; ++kk) {
      int ksb = (kk << 2) + qd;
      half8 af[4], bf[4];
#pragma unroll
      for (int mt = 0; mt < 4; ++mt) {
        int r = (wm << 6) + (mt << 4) + m16;
        int slot = ksb ^ (r & 7);
        af[mt] = *(const half8*)(sA + (r << 6) + (slot << 3));
      }
#pragma unroll
      for (int nt = 0; nt < 4; ++nt) {
        int r = (wn << 6) + (nt << 4) + m16;
        int slot = ksb ^ (r & 7);
        bf[nt] = *(const half8*)(sB + (r << 6) + (slot << 3));
      }
#pragma unroll
      for (int mt = 0; mt < 4; ++mt)
#pragma unroll
        for (int nt = 0; nt < 4; ++nt)
          acc[mt][nt] = __builtin_amdgcn_mfma_f32_16x16x32_f16(af[mt], bf[nt], acc[mt][nt], 0, 0, 0);
    }
    __syncthreads();
  }

  int colBase = n0 + (wn << 6) + m16;
#pragma unroll
  for (int mt = 0; mt < 4; ++mt) {
    int rBase = m0 + (wm << 6) + (mt << 4) + (qd << 2);
#pragma unroll
    for (int nt = 0; nt < 4; ++nt) {
      int col = colBase + (nt << 4);
#pragma unroll
      for (int i = 0; i < 4; ++i) {
        size_t idx = (size_t)(rBase + i) * N + col;
        float v = acc[mt][nt][i];
        if (EP == 1)      ((float*)Cv)[idx] = phi_act(v);
        else if (EP == 2) ((float*)Cv)[idx] = R[idx] + v;
        else if (EP == 3) {
          float r = rintf(v / 0.1f);
          int iq = (int)r + 128;
          iq = iq < 0 ? 0 : (iq > 255 ? 255 : iq);
          ((unsigned short*)Cv)[idx] = f2h(gtab[iq]);
        } else            ((float*)Cv)[idx] = v;
      }
    }
  }
}

// ---------------- stage 1: partial kv/z over an S-chunk --------------------
__global__ __launch_bounds__(256) void kvz_partial(const float* __restrict__ PK,
                                                   const float* __restrict__ V,
                                                   float* __restrict__ P) {
  int c = blockIdx.x, bh = blockIdx.y;
  int b = bh >> 4, h = bh & 15;
  __shared__ float pk[8][64];
  __shared__ float vv[8][64];
  int t = threadIdx.x;
  const size_t base = ((size_t)b * SEQ + (size_t)c * CHROWS) * D_MODEL + h * DH;
  int u = t & 127;
  int lrow = u >> 4;
  int lcol = (u & 15) << 2;
  bool isV = (t >= 128);
  const float* src = isV ? V : PK;
  int dkb = (t >> 4) << 2;
  int deb = (t & 15) << 2;
  float acc[4][4] = {};
  float zacc = 0.f;
  for (int s0 = 0; s0 < CHROWS; s0 += 8) {
    float4 ld = *(const float4*)(src + base + (size_t)(s0 + lrow) * D_MODEL + lcol);
    __syncthreads();
    if (isV) *(float4*)&vv[lrow][lcol] = ld;
    else     *(float4*)&pk[lrow][lcol] = ld;
    __syncthreads();
#pragma unroll
    for (int ss = 0; ss < 8; ++ss) {
      float4 a  = *(const float4*)&pk[ss][dkb];
      float4 bb = *(const float4*)&vv[ss][deb];
      acc[0][0] += a.x * bb.x; acc[0][1] += a.x * bb.y; acc[0][2] += a.x * bb.z; acc[0][3] += a.x * bb.w;
      acc[1][0] += a.y * bb.x; acc[1][1] += a.y * bb.y; acc[1][2] += a.y * bb.z; acc[1][3] += a.y * bb.w;
      acc[2][0] += a.z * bb.x; acc[2][1] += a.z * bb.y; acc[2][2] += a.z * bb.z; acc[2][3] += a.z * bb.w;
      acc[3][0] += a.w * bb.x; acc[3][1] += a.w * bb.y; acc[3][2] += a.w * bb.z; acc[3][3] += a.w * bb.w;
    }
    if (t < 64) {
#pragma unroll
      for (int ss = 0; ss < 8; ++ss) zacc += pk[ss][t];
    }
  }
  float* Pb = P + ((size_t)c * 64 + bh) * PSTRIDE;
#pragma unroll
  for (int i = 0; i < 4; ++i) {
    float4 o; o.x = acc[i][0]; o.y = acc[i][1]; o.z = acc[i][2]; o.w = acc[i][3];
    *(float4*)(Pb + (size_t)(dkb + i) * DH + deb) = o;
  }
  if (t < 64) Pb[4096 + t] = zacc;
}

// ---------------- stage 2: reduce partials over chunks ---------------------
__global__ __launch_bounds__(256) void kvz_reduce(const float* __restrict__ P,
                                                  float* __restrict__ KV,
                                                  float* __restrict__ Z) {
  int bh = blockIdx.x;
  int t = threadIdx.x;
  for (int i = t; i < PSTRIDE; i += 256) {
    float s = 0.f;
#pragma unroll
    for (int c = 0; c < KVCH; ++c)
      s += P[((size_t)c * 64 + bh) * PSTRIDE + i];
    if (i < 4096) KV[(size_t)bh * 4096 + i] = s;
    else          Z[(size_t)bh * 64 + (i - 4096)] = s;
  }
}

// ---------------- attn -> fp16 ---------------------------------------------
__global__ __launch_bounds__(256) void attn_kernel(const float* __restrict__ PQ,
                                                   const float* __restrict__ KVm,
                                                   const float* __restrict__ Z,
                                                   unsigned short* __restrict__ O) {
  int s0 = blockIdx.x << 6;
  int h = blockIdx.y, b = blockIdx.z;
  __shared__ float Pqt[64][64];
  __shared__ float Kv[64][64];
  __shared__ float den[64];
  __shared__ float zsh[64];
  int t = threadIdx.x;
  size_t qbase  = ((size_t)b * SEQ + s0) * D_MODEL + h * DH;
  size_t kvbase = (size_t)(b * NHEADS + h) * (DH * DH);
  int r0 = t >> 4;
  int c4 = (t & 15) << 2;
#pragma unroll
  for (int rr = 0; rr < 4; ++rr) {
    int row = r0 + (rr << 4);
    *(float4*)&Kv[row][c4] = *(const float4*)(KVm + kvbase + (size_t)row * DH + c4);
    float4 q = *(const float4*)(PQ + qbase + (size_t)row * D_MODEL + c4);
    Pqt[c4 + 0][row] = q.x;
    Pqt[c4 + 1][row] = q.y;
    Pqt[c4 + 2][row] = q.z;
    Pqt[c4 + 3][row] = q.w;
  }
  if (t < 16) *(float4*)&zsh[t << 2] = *(const float4*)(Z + (size_t)(b * NHEADS + h) * DH + (t << 2));
  __syncthreads();
  if (t < 64) {
    float d_ = 1e-6f;
#pragma unroll
    for (int dd = 0; dd < 64; ++dd) d_ += Pqt[dd][t] * zsh[dd];
    den[t] = d_;
  }
  __syncthreads();
  int tokb = (t >> 4) << 2, eb = (t & 15) << 2;
  float acc[4][4] = {};
#pragma unroll 8
  for (int dd = 0; dd < 64; ++dd) {
    float4 a  = *(const float4*)&Pqt[dd][tokb];
    float4 bb = *(const float4*)&Kv[dd][eb];
    acc[0][0] += a.x * bb.x; acc[0][1] += a.x * bb.y; acc[0][2] += a.x * bb.z; acc[0][3] += a.x * bb.w;
    acc[1][0] += a.y * bb.x; acc[1][1] += a.y * bb.y; acc[1][2] += a.y * bb.z; acc[1][3] += a.y * bb.w;
    acc[2][0] += a.z * bb.x; acc[2][1] += a.z * bb.y; acc[2][2] += a.z * bb.z; acc[2][3] += a.z * bb.w;
    acc[3][0] += a.w * bb.x; acc[3][1] += a.w * bb.y; acc[3][2] += a.w * bb.z; acc[3][3] += a.w * bb.w;
  }
#pragma unroll
  for (int i = 0; i < 4; ++i) {
    float dv = den[tokb + i];
    ushort4 hv;
    hv.x = f2h(acc[i][0] / dv);
    hv.y = f2h(acc[i][1] / dv);
    hv.z = f2h(acc[i][2] / dv);
    hv.w = f2h(acc[i][3] / dv);
    size_t oidx = ((size_t)b * SEQ + s0 + tokb + i) * D_MODEL + h * DH + eb;
    *(ushort4*)(O + oidx) = hv;
  }
}

extern "C" void kernel_launch(void* const* d_in, const int* in_sizes, int n_in,
                              void* d_out, int out_size, void* d_ws, size_t ws_size,
                              hipStream_t stream) {
  const float* x    = (const float*)d_in[0];
  const float* ln1g = (const float*)d_in[1];
  const float* ln1b = (const float*)d_in[2];
  const float* wq   = (const float*)d_in[3];
  const float* wk   = (const float*)d_in[4];
  const float* wv   = (const float*)d_in[5];
  const float* wo   = (const float*)d_in[6];
  const float* ln2g = (const float*)d_in[7];
  const float* ln2b = (const float*)d_in[8];
  const float* w1   = (const float*)d_in[9];
  const float* w2   = (const float*)d_in[10];
  float* out = (float*)d_out;
  char* ws = (char*)d_ws;

  const size_t MB = 1024 * 1024;
  unsigned short* xn   = (unsigned short*)(ws);
  float*          phiq = (float*)(ws + 32 * MB);
  float*          phik = (float*)(ws + 64 * MB);
  float*          vbuf = (float*)(ws + 96 * MB);
  unsigned short* ffn  = (unsigned short*)(ws + 32 * MB);   // overlays phiq+phik
  unsigned short* w1T  = (unsigned short*)(ws + 96 * MB);   // overlays vbuf
  unsigned short* w2T  = (unsigned short*)(ws + 104 * MB);
  unsigned short* woT  = (unsigned short*)(ws + 128 * MB);

  unsigned short* wqT = (unsigned short*)d_out;
  unsigned short* wkT = wqT + (size_t)D_MODEL * D_MODEL;
  unsigned short* wvT = wkT + (size_t)D_MODEL * D_MODEL;
  float* kvP = (float*)((char*)d_out + 6 * MB);
  float* kv  = (float*)((char*)d_out + 24 * MB);
  float* z   = (float*)((char*)d_out + 25 * MB);

  dim3 blk(256);
  dim3 gcD(D_MODEL / 64, D_MODEL / 64);

  convT<<<gcD, blk, 0, stream>>>(wq, wqT, D_MODEL, D_MODEL);
  convT<<<gcD, blk, 0, stream>>>(wk, wkT, D_MODEL, D_MODEL);
  convT<<<gcD, blk, 0, stream>>>(wv, wvT, D_MODEL, D_MODEL);
  convT<<<gcD, blk, 0, stream>>>(wo, woT, D_MODEL, D_MODEL);

  ln_kernel<<<NTOK, blk, 0, stream>>>(x, ln1g, ln1b, xn);

  dim3 gD(D_MODEL / 128, NTOK / 128);
  mfma_gemm<1><<<gD, blk, 0, stream>>>(xn, wqT, phiq, nullptr, D_MODEL, D_MODEL);
  mfma_gemm<1><<<gD, blk, 0, stream>>>(xn, wkT, phik, nullptr, D_MODEL, D_MODEL);
  mfma_gemm<0><<<gD, blk, 0, stream>>>(xn, wvT, vbuf, nullptr, D_MODEL, D_MODEL);

  kvz_partial<<<dim3(KVCH, BATCH * NHEADS), blk, 0, stream>>>(phik, vbuf, kvP);
  kvz_reduce<<<BATCH * NHEADS, blk, 0, stream>>>(kvP, kv, z);

  attn_kernel<<<dim3(SEQ / 64, NHEADS, BATCH), blk, 0, stream>>>(phiq, kv, z, xn);

  convT<<<dim3(DFF / 64, D_MODEL / 64), blk, 0, stream>>>(w1, w1T, D_MODEL, DFF);
  convT<<<dim3(D_MODEL / 64, DFF / 64), blk, 0, stream>>>(w2, w2T, DFF, D_MODEL);

  mfma_gemm<2><<<gD, blk, 0, stream>>>(xn, woT, out, x, D_MODEL, D_MODEL);

  ln_kernel<<<NTOK, blk, 0, stream>>>(out, ln2g, ln2b, xn);

  dim3 gF(DFF / 128, NTOK / 128);
  mfma_gemm<3><<<gF, blk, 0, stream>>>(xn, w1T, ffn, nullptr, DFF, D_MODEL);

  mfma_gemm<2><<<gD, blk, 0, stream>>>(ffn, w2T, out, out, D_MODEL, DFF);
}

// Round 7
// 482.469 us; speedup vs baseline: 6.9829x; 1.0298x over previous
//
#include <hip/hip_runtime.h>
#include <cstdint>
#include <cstddef>

// PiFormerBlock, MFMA fp16 version, round 7.
//   x = x + linattn(LN1(x)) @ wo ;  x = x + gelu_lut(LN2(x) @ w1) @ w2
// Round-7 changes:
//  - Fused qkv GEMM: N=3072 (wq|wk|wv concatenated, contiguous in scratch).
//    Grid 512 -> 1536 blocks (occupancy), A read once instead of 3x.
//    Epilogue selects q/k/v slab by column block (128 | 1024 boundaries),
//    phi for q/k, plain for v; outputs fp16.
//  - phiq/phik/vbuf stored fp16 (was fp32): halves qkv writes + kvz/attn reads.
//  - kvz_partial / attn_kernel read fp16.
//
// ws layout (bytes):
//   0      xn    [8192x1024] fp16 (16MB)  (reused as attn out)
//   32MB   phiq  fp16 (16MB) \
//   48MB   phik  fp16 (16MB)  >-- contiguous qkv slab; later overlaid by
//   64MB   vbuf  fp16 (16MB) /    ffn fp16 [8192x4096] (64MB @ 32MB)
//   96MB   w1T   fp16 (8MB) | 104MB w2T fp16 (8MB) | 128MB woT fp16 (2MB)
// d_out scratch (dead before wo-GEMM writes it):
//   0MB wqkvT (6MB) | 6MB kv partials (17.04MB) | 24MB kv (1MB) | 25MB z

#define D_MODEL 1024
#define SEQ     2048
#define BATCH   4
#define NTOK    8192
#define NHEADS  16
#define DH      64
#define DFF     4096
#define KVCH    16
#define CHROWS  (SEQ / KVCH)
#define PSTRIDE 4160

typedef _Float16 half8 __attribute__((ext_vector_type(8)));
typedef float f32x4 __attribute__((ext_vector_type(4)));

__device__ __forceinline__ unsigned short f2h(float x) {
  _Float16 h = (_Float16)x;
  union { _Float16 h; unsigned short u; } c; c.h = h; return c.u;
}
__device__ __forceinline__ float h2f(unsigned short u) {
  union { unsigned short u; _Float16 h; } c; c.u = u; return (float)c.h;
}

__device__ __forceinline__ float phi_act(float x) {
  return x > 0.f ? x + 1.f : expf(x);
}

__device__ __forceinline__ float gelu_exact(float v) {
  float c = 0.7978845608028654f;
  float t = tanhf(c * (v + 0.044715f * v * v * v));
  return 0.5f * v * (1.f + t);
}

__device__ __forceinline__ void gl_lds16(const void* g, void* l) {
  __builtin_amdgcn_global_load_lds(
      (const __attribute__((address_space(1))) unsigned int*)g,
      (__attribute__((address_space(3))) unsigned int*)l, 16, 0, 0);
}

// ---------------- transpose-convert: W fp32 [K,N] -> WT fp16 [N,K] ----------
__global__ __launch_bounds__(256) void convT(const float* __restrict__ W,
                                             unsigned short* __restrict__ WT,
                                             int K, int N) {
  __shared__ float tile[64][65];
  int kb = blockIdx.y << 6, nb = blockIdx.x << 6;
  int t = threadIdx.x;
  int rr = t >> 4, cc = (t & 15) << 2;
#pragma unroll
  for (int i = 0; i < 4; ++i) {
    int r = rr + (i << 4);
    float4 v = *(const float4*)(W + (size_t)(kb + r) * N + nb + cc);
    tile[r][cc] = v.x; tile[r][cc + 1] = v.y; tile[r][cc + 2] = v.z; tile[r][cc + 3] = v.w;
  }
  __syncthreads();
#pragma unroll
  for (int i = 0; i < 4; ++i) {
    int n = rr + (i << 4);
    ushort4 o;
    o.x = f2h(tile[cc + 0][n]); o.y = f2h(tile[cc + 1][n]);
    o.z = f2h(tile[cc + 2][n]); o.w = f2h(tile[cc + 3][n]);
    *(ushort4*)(WT + (size_t)(nb + n) * K + kb + cc) = o;
  }
}

// ---------------- LayerNorm -> fp16 ----------------------------------------
__global__ __launch_bounds__(256) void ln_kernel(const float* __restrict__ X,
                                                 const float* __restrict__ g,
                                                 const float* __restrict__ b,
                                                 unsigned short* __restrict__ Y) {
  int tok = blockIdx.x;
  int t = threadIdx.x;
  const float4* xr = (const float4*)(X + (size_t)tok * D_MODEL);
  float4 v = xr[t];
  float s  = v.x + v.y + v.z + v.w;
  float s2 = v.x * v.x + v.y * v.y + v.z * v.z + v.w * v.w;
#pragma unroll
  for (int o = 32; o > 0; o >>= 1) {
    s  += __shfl_down(s, o);
    s2 += __shfl_down(s2, o);
  }
  __shared__ float red[8];
  __shared__ float mu_s, rs_s;
  int wid = t >> 6;
  if ((t & 63) == 0) { red[wid] = s; red[wid + 4] = s2; }
  __syncthreads();
  if (t == 0) {
    float ts  = red[0] + red[1] + red[2] + red[3];
    float ts2 = red[4] + red[5] + red[6] + red[7];
    float mu  = ts * (1.f / D_MODEL);
    float var = ts2 * (1.f / D_MODEL) - mu * mu;
    mu_s = mu;
    rs_s = rsqrtf(var + 1e-5f);
  }
  __syncthreads();
  float mu = mu_s, rs = rs_s;
  float4 gv = ((const float4*)g)[t];
  float4 bv = ((const float4*)b)[t];
  ushort4 hv;
  hv.x = f2h((v.x - mu) * rs * gv.x + bv.x);
  hv.y = f2h((v.y - mu) * rs * gv.y + bv.y);
  hv.z = f2h((v.z - mu) * rs * gv.z + bv.z);
  hv.w = f2h((v.w - mu) * rs * gv.w + bv.w);
  ((ushort4*)(Y + (size_t)tok * D_MODEL))[t] = hv;
}

// ---------------- MFMA GEMM: C[M,N] = A[M,K] @ BT[N,K]^T (fp16 in) ---------
// EP: 0 fp32 | 2 +R fp32 | 3 gelu-LUT fp16 | 4 fused qkv (phi on q/k) fp16
template <int EP>
__global__ __launch_bounds__(256, 4) void mfma_gemm(
    const unsigned short* __restrict__ A,
    const unsigned short* __restrict__ BT,
    void* Cv, const float* R, int N, int K) {
  __shared__ unsigned short smem[2 * 8192];
  __shared__ float gtab[EP == 3 ? 256 : 1];
  unsigned short* sA = smem;
  unsigned short* sB = smem + 8192;

  int t = threadIdx.x;
  if (EP == 3) gtab[t & 255] = gelu_exact((float)((t & 255) - 128) * 0.1f);

  // XCD-aware swizzle (8 XCDs, round-robin on linear block id).
  int bm, bn;
  {
    int L = blockIdx.y * gridDim.x + blockIdx.x;
    if ((gridDim.y & 7) == 0) {
      int xcd = L & 7, wi = L >> 3;
      int mPerX = gridDim.y >> 3;
      bm = xcd * mPerX + wi / gridDim.x;
      bn = wi % gridDim.x;
    } else {
      bn = blockIdx.x; bm = blockIdx.y;
    }
  }

  int w = t >> 6, l = t & 63;
  int rl = l >> 3, cl = l & 7;
  int gseg = (cl ^ rl) << 4;        // swizzled 16B segment (bytes)
  int m0 = bm << 7;
  int n0 = bn << 7;
  size_t strideB = (size_t)K * 2;

  const char* gA[4]; const char* gB[4];
  int ldsOff[4];
  for (int j = 0; j < 4; ++j) {
    int row = (w << 5) + (j << 3) + rl;
    gA[j] = (const char*)A + (size_t)(m0 + row) * strideB + gseg;
    gB[j] = (const char*)BT + (size_t)(n0 + row) * strideB + gseg;
    ldsOff[j] = ((w << 5) + (j << 3)) << 6;
  }

  int wm = w >> 1, wn = w & 1;
  int m16 = l & 15, qd = l >> 4;

  f32x4 acc[4][4];
#pragma unroll
  for (int i = 0; i < 4; ++i)
#pragma unroll
    for (int j = 0; j < 4; ++j) acc[i][j] = (f32x4){0.f, 0.f, 0.f, 0.f};

  for (int k0 = 0; k0 < K; k0 += 64) {
    size_t kb = (size_t)k0 * 2;
#pragma unroll
    for (int j = 0; j < 4; ++j) {
      gl_lds16(gA[j] + kb, sA + ldsOff[j]);
      gl_lds16(gB[j] + kb, sB + ldsOff[j]);
    }
    __syncthreads();
#pragma unroll
    for (int kk = 0; kk < 2; ++kk) {
      int ksb = (kk << 2) + qd;
      half8 af[4], bf[4];
#pragma unroll
      for (int mt = 0; mt < 4; ++mt) {
        int r = (wm << 6) + (mt << 4) + m16;
        int slot = ksb ^ (r & 7);
        af[mt] = *(const half8*)(sA + (r << 6) + (slot << 3));
      }
#pragma unroll
      for (int nt = 0; nt < 4; ++nt) {
        int r = (wn << 6) + (nt << 4) + m16;
        int slot = ksb ^ (r & 7);
        bf[nt] = *(const half8*)(sB + (r << 6) + (slot << 3));
      }
#pragma unroll
      for (int mt = 0; mt < 4; ++mt)
#pragma unroll
        for (int nt = 0; nt < 4; ++nt)
          acc[mt][nt] = __builtin_amdgcn_mfma_f32_16x16x32_f16(af[mt], bf[nt], acc[mt][nt], 0, 0, 0);
    }
    __syncthreads();
  }

  // EP=4: destination slab by column block (n0 is 128-aligned, slabs 1024-wide)
  int sel = n0 >> 10;                       // 0=q 1=k 2=v
  size_t slab = (size_t)sel * ((size_t)NTOK * D_MODEL);
  int colL = (n0 & 1023) + (wn << 6) + m16; // local col within slab

  int colBase = n0 + (wn << 6) + m16;
#pragma unroll
  for (int mt = 0; mt < 4; ++mt) {
    int rBase = m0 + (wm << 6) + (mt << 4) + (qd << 2);
#pragma unroll
    for (int nt = 0; nt < 4; ++nt) {
      int col = colBase + (nt << 4);
#pragma unroll
      for (int i = 0; i < 4; ++i) {
        float v = acc[mt][nt][i];
        if (EP == 4) {
          if (sel < 2) v = phi_act(v);
          size_t idx = slab + (size_t)(rBase + i) * D_MODEL + colL + (nt << 4);
          ((unsigned short*)Cv)[idx] = f2h(v);
        } else {
          size_t idx = (size_t)(rBase + i) * N + col;
          if (EP == 2)      ((float*)Cv)[idx] = R[idx] + v;
          else if (EP == 3) {
            float r = rintf(v / 0.1f);
            int iq = (int)r + 128;
            iq = iq < 0 ? 0 : (iq > 255 ? 255 : iq);
            ((unsigned short*)Cv)[idx] = f2h(gtab[iq]);
          } else          ((float*)Cv)[idx] = v;
        }
      }
    }
  }
}

// ---------------- stage 1: partial kv/z over an S-chunk (fp16 in) ----------
__global__ __launch_bounds__(256) void kvz_partial(const unsigned short* __restrict__ PK,
                                                   const unsigned short* __restrict__ V,
                                                   float* __restrict__ P) {
  int c = blockIdx.x, bh = blockIdx.y;
  int b = bh >> 4, h = bh & 15;
  __shared__ float pk[8][64];
  __shared__ float vv[8][64];
  int t = threadIdx.x;
  const size_t base = ((size_t)b * SEQ + (size_t)c * CHROWS) * D_MODEL + h * DH;
  int u = t & 127;
  int lrow = u >> 4;           // 0..7
  int lcol = (u & 15) << 2;    // 0..60
  bool isV = (t >= 128);
  const unsigned short* src = isV ? V : PK;
  int dkb = (t >> 4) << 2;
  int deb = (t & 15) << 2;
  float acc[4][4] = {};
  float zacc = 0.f;
  for (int s0 = 0; s0 < CHROWS; s0 += 8) {
    ushort4 ld = *(const ushort4*)(src + base + (size_t)(s0 + lrow) * D_MODEL + lcol);
    float f0 = h2f(ld.x), f1 = h2f(ld.y), f2 = h2f(ld.z), f3 = h2f(ld.w);
    __syncthreads();
    if (isV) { vv[lrow][lcol] = f0; vv[lrow][lcol+1] = f1; vv[lrow][lcol+2] = f2; vv[lrow][lcol+3] = f3; }
    else     { pk[lrow][lcol] = f0; pk[lrow][lcol+1] = f1; pk[lrow][lcol+2] = f2; pk[lrow][lcol+3] = f3; }
    __syncthreads();
#pragma unroll
    for (int ss = 0; ss < 8; ++ss) {
      float4 a  = *(const float4*)&pk[ss][dkb];
      float4 bb = *(const float4*)&vv[ss][deb];
      acc[0][0] += a.x * bb.x; acc[0][1] += a.x * bb.y; acc[0][2] += a.x * bb.z; acc[0][3] += a.x * bb.w;
      acc[1][0] += a.y * bb.x; acc[1][1] += a.y * bb.y; acc[1][2] += a.y * bb.z; acc[1][3] += a.y * bb.w;
      acc[2][0] += a.z * bb.x; acc[2][1] += a.z * bb.y; acc[2][2] += a.z * bb.z; acc[2][3] += a.z * bb.w;
      acc[3][0] += a.w * bb.x; acc[3][1] += a.w * bb.y; acc[3][2] += a.w * bb.z; acc[3][3] += a.w * bb.w;
    }
    if (t < 64) {
#pragma unroll
      for (int ss = 0; ss < 8; ++ss) zacc += pk[ss][t];
    }
  }
  float* Pb = P + ((size_t)c * 64 + bh) * PSTRIDE;
#pragma unroll
  for (int i = 0; i < 4; ++i) {
    float4 o; o.x = acc[i][0]; o.y = acc[i][1]; o.z = acc[i][2]; o.w = acc[i][3];
    *(float4*)(Pb + (size_t)(dkb + i) * DH + deb) = o;
  }
  if (t < 64) Pb[4096 + t] = zacc;
}

// ---------------- stage 2: reduce partials over chunks ---------------------
__global__ __launch_bounds__(256) void kvz_reduce(const float* __restrict__ P,
                                                  float* __restrict__ KV,
                                                  float* __restrict__ Z) {
  int bh = blockIdx.x;
  int t = threadIdx.x;
  for (int i = t; i < PSTRIDE; i += 256) {
    float s = 0.f;
#pragma unroll
    for (int c = 0; c < KVCH; ++c)
      s += P[((size_t)c * 64 + bh) * PSTRIDE + i];
    if (i < 4096) KV[(size_t)bh * 4096 + i] = s;
    else          Z[(size_t)bh * 64 + (i - 4096)] = s;
  }
}

// ---------------- attn (fp16 phiq in) -> fp16 ------------------------------
__global__ __launch_bounds__(256) void attn_kernel(const unsigned short* __restrict__ PQ,
                                                   const float* __restrict__ KVm,
                                                   const float* __restrict__ Z,
                                                   unsigned short* __restrict__ O) {
  int s0 = blockIdx.x << 6;
  int h = blockIdx.y, b = blockIdx.z;
  __shared__ float Pqt[64][64];
  __shared__ float Kv[64][64];
  __shared__ float den[64];
  __shared__ float zsh[64];
  int t = threadIdx.x;
  size_t qbase  = ((size_t)b * SEQ + s0) * D_MODEL + h * DH;
  size_t kvbase = (size_t)(b * NHEADS + h) * (DH * DH);
  int r0 = t >> 4;
  int c4 = (t & 15) << 2;
#pragma unroll
  for (int rr = 0; rr < 4; ++rr) {
    int row = r0 + (rr << 4);
    *(float4*)&Kv[row][c4] = *(const float4*)(KVm + kvbase + (size_t)row * DH + c4);
    ushort4 q = *(const ushort4*)(PQ + qbase + (size_t)row * D_MODEL + c4);
    Pqt[c4 + 0][row] = h2f(q.x);
    Pqt[c4 + 1][row] = h2f(q.y);
    Pqt[c4 + 2][row] = h2f(q.z);
    Pqt[c4 + 3][row] = h2f(q.w);
  }
  if (t < 16) *(float4*)&zsh[t << 2] = *(const float4*)(Z + (size_t)(b * NHEADS + h) * DH + (t << 2));
  __syncthreads();
  if (t < 64) {
    float d_ = 1e-6f;
#pragma unroll
    for (int dd = 0; dd < 64; ++dd) d_ += Pqt[dd][t] * zsh[dd];
    den[t] = d_;
  }
  __syncthreads();
  int tokb = (t >> 4) << 2, eb = (t & 15) << 2;
  float acc[4][4] = {};
#pragma unroll 8
  for (int dd = 0; dd < 64; ++dd) {
    float4 a  = *(const float4*)&Pqt[dd][tokb];
    float4 bb = *(const float4*)&Kv[dd][eb];
    acc[0][0] += a.x * bb.x; acc[0][1] += a.x * bb.y; acc[0][2] += a.x * bb.z; acc[0][3] += a.x * bb.w;
    acc[1][0] += a.y * bb.x; acc[1][1] += a.y * bb.y; acc[1][2] += a.y * bb.z; acc[1][3] += a.y * bb.w;
    acc[2][0] += a.z * bb.x; acc[2][1] += a.z * bb.y; acc[2][2] += a.z * bb.z; acc[2][3] += a.z * bb.w;
    acc[3][0] += a.w * bb.x; acc[3][1] += a.w * bb.y; acc[3][2] += a.w * bb.z; acc[3][3] += a.w * bb.w;
  }
#pragma unroll
  for (int i = 0; i < 4; ++i) {
    float dv = den[tokb + i];
    ushort4 hv;
    hv.x = f2h(acc[i][0] / dv);
    hv.y = f2h(acc[i][1] / dv);
    hv.z = f2h(acc[i][2] / dv);
    hv.w = f2h(acc[i][3] / dv);
    size_t oidx = ((size_t)b * SEQ + s0 + tokb + i) * D_MODEL + h * DH + eb;
    *(ushort4*)(O + oidx) = hv;
  }
}

extern "C" void kernel_launch(void* const* d_in, const int* in_sizes, int n_in,
                              void* d_out, int out_size, void* d_ws, size_t ws_size,
                              hipStream_t stream) {
  const float* x    = (const float*)d_in[0];
  const float* ln1g = (const float*)d_in[1];
  const float* ln1b = (const float*)d_in[2];
  const float* wq   = (const float*)d_in[3];
  const float* wk   = (const float*)d_in[4];
  const float* wv   = (const float*)d_in[5];
  const float* wo   = (const float*)d_in[6];
  const float* ln2g = (const float*)d_in[7];
  const float* ln2b = (const float*)d_in[8];
  const float* w1   = (const float*)d_in[9];
  const float* w2   = (const float*)d_in[10];
  float* out = (float*)d_out;
  char* ws = (char*)d_ws;

  const size_t MB = 1024 * 1024;
  unsigned short* xn   = (unsigned short*)(ws);
  unsigned short* qkv  = (unsigned short*)(ws + 32 * MB);  // phiq|phik|vbuf fp16
  unsigned short* phiq = qkv;
  unsigned short* phik = qkv + (size_t)NTOK * D_MODEL;
  unsigned short* vbuf = qkv + 2 * (size_t)NTOK * D_MODEL;
  unsigned short* ffn  = (unsigned short*)(ws + 32 * MB);  // overlays qkv slab
  unsigned short* w1T  = (unsigned short*)(ws + 96 * MB);
  unsigned short* w2T  = (unsigned short*)(ws + 104 * MB);
  unsigned short* woT  = (unsigned short*)(ws + 128 * MB);

  // d_out as scratch until wo-GEMM writes it
  unsigned short* wqkvT = (unsigned short*)d_out;          // [3072,1024] fp16
  float* kvP = (float*)((char*)d_out + 6 * MB);
  float* kv  = (float*)((char*)d_out + 24 * MB);
  float* z   = (float*)((char*)d_out + 25 * MB);

  dim3 blk(256);
  dim3 gcD(D_MODEL / 64, D_MODEL / 64);

  convT<<<gcD, blk, 0, stream>>>(wq, wqkvT, D_MODEL, D_MODEL);
  convT<<<gcD, blk, 0, stream>>>(wk, wqkvT + (size_t)D_MODEL * D_MODEL, D_MODEL, D_MODEL);
  convT<<<gcD, blk, 0, stream>>>(wv, wqkvT + 2 * (size_t)D_MODEL * D_MODEL, D_MODEL, D_MODEL);
  convT<<<gcD, blk, 0, stream>>>(wo, woT, D_MODEL, D_MODEL);

  ln_kernel<<<NTOK, blk, 0, stream>>>(x, ln1g, ln1b, xn);

  // fused qkv: C[8192,3072] -> phi(q),phi(k) | v, fp16 slabs
  dim3 gQKV(3 * D_MODEL / 128, NTOK / 128);
  mfma_gemm<4><<<gQKV, blk, 0, stream>>>(xn, wqkvT, qkv, nullptr, 3 * D_MODEL, D_MODEL);

  kvz_partial<<<dim3(KVCH, BATCH * NHEADS), blk, 0, stream>>>(phik, vbuf, kvP);
  kvz_reduce<<<BATCH * NHEADS, blk, 0, stream>>>(kvP, kv, z);

  attn_kernel<<<dim3(SEQ / 64, NHEADS, BATCH), blk, 0, stream>>>(phiq, kv, z, xn);

  convT<<<dim3(DFF / 64, D_MODEL / 64), blk, 0, stream>>>(w1, w1T, D_MODEL, DFF);
  convT<<<dim3(D_MODEL / 64, DFF / 64), blk, 0, stream>>>(w2, w2T, DFF, D_MODEL);

  dim3 gD(D_MODEL / 128, NTOK / 128);
  mfma_gemm<2><<<gD, blk, 0, stream>>>(xn, woT, out, x, D_MODEL, D_MODEL);

  ln_kernel<<<NTOK, blk, 0, stream>>>(out, ln2g, ln2b, xn);

  dim3 gF(DFF / 128, NTOK / 128);
  mfma_gemm<3><<<gF, blk, 0, stream>>>(xn, w1T, ffn, nullptr, DFF, D_MODEL);

  mfma_gemm<2><<<gD, blk, 0, stream>>>(ffn, w2T, out, out, D_MODEL, DFF);
}

// Round 8
// 454.133 us; speedup vs baseline: 7.4186x; 1.0624x over previous
//
#include <hip/hip_runtime.h>
#include <cstdint>
#include <cstddef>

// PiFormerBlock, MFMA fp16 version, round 8.
//   x = x + linattn(LN1(x)) @ wo ;  x = x + gelu_lut(LN2(x) @ w1) @ w2
// Round-8 change: templated BK in mfma_gemm. w2/wo are grid-starved (512
// blocks = 2 blocks/CU, can't raise occupancy), so halve their barrier-drain
// count instead: BK=128 (64KB LDS, still 2 blocks/CU -> free), 64 MFMA/wave
// per K-iter. qkv/w1 stay BK=64 (they run 4 blocks/CU; 64KB LDS would halve
// that -- the m132 trap).
//
// ws layout (bytes):
//   0      xn    [8192x1024] fp16 (16MB)  (reused as attn out)
//   32MB   phiq  fp16 (16MB) \
//   48MB   phik  fp16 (16MB)  >-- contiguous qkv slab; later overlaid by
//   64MB   vbuf  fp16 (16MB) /    ffn fp16 [8192x4096] (64MB @ 32MB)
//   96MB   w1T   fp16 (8MB) | 104MB w2T fp16 (8MB) | 128MB woT fp16 (2MB)
// d_out scratch (dead before wo-GEMM writes it):
//   0MB wqkvT (6MB) | 6MB kv partials (17.04MB) | 24MB kv (1MB) | 25MB z

#define D_MODEL 1024
#define SEQ     2048
#define BATCH   4
#define NTOK    8192
#define NHEADS  16
#define DH      64
#define DFF     4096
#define KVCH    16
#define CHROWS  (SEQ / KVCH)
#define PSTRIDE 4160

typedef _Float16 half8 __attribute__((ext_vector_type(8)));
typedef float f32x4 __attribute__((ext_vector_type(4)));

__device__ __forceinline__ unsigned short f2h(float x) {
  _Float16 h = (_Float16)x;
  union { _Float16 h; unsigned short u; } c; c.h = h; return c.u;
}
__device__ __forceinline__ float h2f(unsigned short u) {
  union { unsigned short u; _Float16 h; } c; c.u = u; return (float)c.h;
}

__device__ __forceinline__ float phi_act(float x) {
  return x > 0.f ? x + 1.f : expf(x);
}

__device__ __forceinline__ float gelu_exact(float v) {
  float c = 0.7978845608028654f;
  float t = tanhf(c * (v + 0.044715f * v * v * v));
  return 0.5f * v * (1.f + t);
}

__device__ __forceinline__ void gl_lds16(const void* g, void* l) {
  __builtin_amdgcn_global_load_lds(
      (const __attribute__((address_space(1))) unsigned int*)g,
      (__attribute__((address_space(3))) unsigned int*)l, 16, 0, 0);
}

// ---------------- transpose-convert: W fp32 [K,N] -> WT fp16 [N,K] ----------
__global__ __launch_bounds__(256) void convT(const float* __restrict__ W,
                                             unsigned short* __restrict__ WT,
                                             int K, int N) {
  __shared__ float tile[64][65];
  int kb = blockIdx.y << 6, nb = blockIdx.x << 6;
  int t = threadIdx.x;
  int rr = t >> 4, cc = (t & 15) << 2;
#pragma unroll
  for (int i = 0; i < 4; ++i) {
    int r = rr + (i << 4);
    float4 v = *(const float4*)(W + (size_t)(kb + r) * N + nb + cc);
    tile[r][cc] = v.x; tile[r][cc + 1] = v.y; tile[r][cc + 2] = v.z; tile[r][cc + 3] = v.w;
  }
  __syncthreads();
#pragma unroll
  for (int i = 0; i < 4; ++i) {
    int n = rr + (i << 4);
    ushort4 o;
    o.x = f2h(tile[cc + 0][n]); o.y = f2h(tile[cc + 1][n]);
    o.z = f2h(tile[cc + 2][n]); o.w = f2h(tile[cc + 3][n]);
    *(ushort4*)(WT + (size_t)(nb + n) * K + kb + cc) = o;
  }
}

// ---------------- LayerNorm -> fp16 ----------------------------------------
__global__ __launch_bounds__(256) void ln_kernel(const float* __restrict__ X,
                                                 const float* __restrict__ g,
                                                 const float* __restrict__ b,
                                                 unsigned short* __restrict__ Y) {
  int tok = blockIdx.x;
  int t = threadIdx.x;
  const float4* xr = (const float4*)(X + (size_t)tok * D_MODEL);
  float4 v = xr[t];
  float s  = v.x + v.y + v.z + v.w;
  float s2 = v.x * v.x + v.y * v.y + v.z * v.z + v.w * v.w;
#pragma unroll
  for (int o = 32; o > 0; o >>= 1) {
    s  += __shfl_down(s, o);
    s2 += __shfl_down(s2, o);
  }
  __shared__ float red[8];
  __shared__ float mu_s, rs_s;
  int wid = t >> 6;
  if ((t & 63) == 0) { red[wid] = s; red[wid + 4] = s2; }
  __syncthreads();
  if (t == 0) {
    float ts  = red[0] + red[1] + red[2] + red[3];
    float ts2 = red[4] + red[5] + red[6] + red[7];
    float mu  = ts * (1.f / D_MODEL);
    float var = ts2 * (1.f / D_MODEL) - mu * mu;
    mu_s = mu;
    rs_s = rsqrtf(var + 1e-5f);
  }
  __syncthreads();
  float mu = mu_s, rs = rs_s;
  float4 gv = ((const float4*)g)[t];
  float4 bv = ((const float4*)b)[t];
  ushort4 hv;
  hv.x = f2h((v.x - mu) * rs * gv.x + bv.x);
  hv.y = f2h((v.y - mu) * rs * gv.y + bv.y);
  hv.z = f2h((v.z - mu) * rs * gv.z + bv.z);
  hv.w = f2h((v.w - mu) * rs * gv.w + bv.w);
  ((ushort4*)(Y + (size_t)tok * D_MODEL))[t] = hv;
}

// ---------------- MFMA GEMM: C[M,N] = A[M,K] @ BT[N,K]^T (fp16 in) ---------
// EP: 0 fp32 | 2 +R fp32 | 3 gelu-LUT fp16 | 4 fused qkv (phi on q/k) fp16
// BK: K-chunk per barrier (64 -> 32KB LDS, 128 -> 64KB LDS)
template <int EP, int BK>
__global__ __launch_bounds__(256, (BK == 64) ? 4 : 2) void mfma_gemm(
    const unsigned short* __restrict__ A,
    const unsigned short* __restrict__ BT,
    void* Cv, const float* R, int N, int K) {
  constexpr int SEGS = BK / 8;     // 16B segments per row
  constexpr int RPC  = 64 / SEGS;  // rows covered by one gl_lds16 call
  constexpr int NJ   = 32 / RPC;   // calls per wave per tile (32 rows/wave)
  __shared__ unsigned short smem[2 * 128 * BK];
  __shared__ float gtab[EP == 3 ? 256 : 1];
  unsigned short* sA = smem;
  unsigned short* sB = smem + 128 * BK;

  int t = threadIdx.x;
  if (EP == 3) gtab[t & 255] = gelu_exact((float)((t & 255) - 128) * 0.1f);

  // XCD-aware swizzle (8 XCDs, round-robin on linear block id).
  int bm, bn;
  {
    int L = blockIdx.y * gridDim.x + blockIdx.x;
    if ((gridDim.y & 7) == 0) {
      int xcd = L & 7, wi = L >> 3;
      int mPerX = gridDim.y >> 3;
      bm = xcd * mPerX + wi / gridDim.x;
      bn = wi % gridDim.x;
    } else {
      bn = blockIdx.x; bm = blockIdx.y;
    }
  }

  int w = t >> 6, l = t & 63;
  int lrow = l / SEGS;             // row within call group
  int lseg = l & (SEGS - 1);       // 16B segment within row
  int m0 = bm << 7;
  int n0 = bn << 7;
  size_t strideB = (size_t)K * 2;

  const char* gA[NJ]; const char* gB[NJ];
  int ldsOff[NJ];
#pragma unroll
  for (int j = 0; j < NJ; ++j) {
    int row = (w << 5) + j * RPC + lrow;
    int gso = (lseg ^ (row & 7)) << 4;   // swizzled segment offset (bytes)
    gA[j] = (const char*)A + (size_t)(m0 + row) * strideB + gso;
    gB[j] = (const char*)BT + (size_t)(n0 + row) * strideB + gso;
    ldsOff[j] = ((w << 5) + j * RPC) * BK;  // shorts
  }

  int wm = w >> 1, wn = w & 1;
  int m16 = l & 15, qd = l >> 4;

  f32x4 acc[4][4];
#pragma unroll
  for (int i = 0; i < 4; ++i)
#pragma unroll
    for (int j = 0; j < 4; ++j) acc[i][j] = (f32x4){0.f, 0.f, 0.f, 0.f};

  for (int k0 = 0; k0 < K; k0 += BK) {
    size_t kb = (size_t)k0 * 2;
#pragma unroll
    for (int j = 0; j < NJ; ++j) {
      gl_lds16(gA[j] + kb, sA + ldsOff[j]);
      gl_lds16(gB[j] + kb, sB + ldsOff[j]);
    }
    __syncthreads();
#pragma unroll
    for (int kk = 0; kk < BK / 32; ++kk) {
      int ksb = (kk << 2) + qd;
      half8 af[4], bf[4];
#pragma unroll
      for (int mt = 0; mt < 4; ++mt) {
        int r = (wm << 6) + (mt << 4) + m16;
        int slot = ksb ^ (r & 7);
        af[mt] = *(const half8*)(sA + r * BK + (slot << 3));
      }
#pragma unroll
      for (int nt = 0; nt < 4; ++nt) {
        int r = (wn << 6) + (nt << 4) + m16;
        int slot = ksb ^ (r & 7);
        bf[nt] = *(const half8*)(sB + r * BK + (slot << 3));
      }
#pragma unroll
      for (int mt = 0; mt < 4; ++mt)
#pragma unroll
        for (int nt = 0; nt < 4; ++nt)
          acc[mt][nt] = __builtin_amdgcn_mfma_f32_16x16x32_f16(af[mt], bf[nt], acc[mt][nt], 0, 0, 0);
    }
    __syncthreads();
  }

  // EP=4: destination slab by column block (n0 is 128-aligned, slabs 1024-wide)
  int sel = n0 >> 10;                       // 0=q 1=k 2=v
  size_t slab = (size_t)sel * ((size_t)NTOK * D_MODEL);
  int colL = (n0 & 1023) + (wn << 6) + m16; // local col within slab

  int colBase = n0 + (wn << 6) + m16;
#pragma unroll
  for (int mt = 0; mt < 4; ++mt) {
    int rBase = m0 + (wm << 6) + (mt << 4) + (qd << 2);
#pragma unroll
    for (int nt = 0; nt < 4; ++nt) {
      int col = colBase + (nt << 4);
#pragma unroll
      for (int i = 0; i < 4; ++i) {
        float v = acc[mt][nt][i];
        if (EP == 4) {
          if (sel < 2) v = phi_act(v);
          size_t idx = slab + (size_t)(rBase + i) * D_MODEL + colL + (nt << 4);
          ((unsigned short*)Cv)[idx] = f2h(v);
        } else {
          size_t idx = (size_t)(rBase + i) * N + col;
          if (EP == 2)      ((float*)Cv)[idx] = R[idx] + v;
          else if (EP == 3) {
            float r = rintf(v / 0.1f);
            int iq = (int)r + 128;
            iq = iq < 0 ? 0 : (iq > 255 ? 255 : iq);
            ((unsigned short*)Cv)[idx] = f2h(gtab[iq]);
          } else          ((float*)Cv)[idx] = v;
        }
      }
    }
  }
}

// ---------------- stage 1: partial kv/z over an S-chunk (fp16 in) ----------
__global__ __launch_bounds__(256) void kvz_partial(const unsigned short* __restrict__ PK,
                                                   const unsigned short* __restrict__ V,
                                                   float* __restrict__ P) {
  int c = blockIdx.x, bh = blockIdx.y;
  int b = bh >> 4, h = bh & 15;
  __shared__ float pk[8][64];
  __shared__ float vv[8][64];
  int t = threadIdx.x;
  const size_t base = ((size_t)b * SEQ + (size_t)c * CHROWS) * D_MODEL + h * DH;
  int u = t & 127;
  int lrow = u >> 4;
  int lcol = (u & 15) << 2;
  bool isV = (t >= 128);
  const unsigned short* src = isV ? V : PK;
  int dkb = (t >> 4) << 2;
  int deb = (t & 15) << 2;
  float acc[4][4] = {};
  float zacc = 0.f;
  for (int s0 = 0; s0 < CHROWS; s0 += 8) {
    ushort4 ld = *(const ushort4*)(src + base + (size_t)(s0 + lrow) * D_MODEL + lcol);
    float f0 = h2f(ld.x), f1 = h2f(ld.y), f2 = h2f(ld.z), f3 = h2f(ld.w);
    __syncthreads();
    if (isV) { vv[lrow][lcol] = f0; vv[lrow][lcol+1] = f1; vv[lrow][lcol+2] = f2; vv[lrow][lcol+3] = f3; }
    else     { pk[lrow][lcol] = f0; pk[lrow][lcol+1] = f1; pk[lrow][lcol+2] = f2; pk[lrow][lcol+3] = f3; }
    __syncthreads();
#pragma unroll
    for (int ss = 0; ss < 8; ++ss) {
      float4 a  = *(const float4*)&pk[ss][dkb];
      float4 bb = *(const float4*)&vv[ss][deb];
      acc[0][0] += a.x * bb.x; acc[0][1] += a.x * bb.y; acc[0][2] += a.x * bb.z; acc[0][3] += a.x * bb.w;
      acc[1][0] += a.y * bb.x; acc[1][1] += a.y * bb.y; acc[1][2] += a.y * bb.z; acc[1][3] += a.y * bb.w;
      acc[2][0] += a.z * bb.x; acc[2][1] += a.z * bb.y; acc[2][2] += a.z * bb.z; acc[2][3] += a.z * bb.w;
      acc[3][0] += a.w * bb.x; acc[3][1] += a.w * bb.y; acc[3][2] += a.w * bb.z; acc[3][3] += a.w * bb.w;
    }
    if (t < 64) {
#pragma unroll
      for (int ss = 0; ss < 8; ++ss) zacc += pk[ss][t];
    }
  }
  float* Pb = P + ((size_t)c * 64 + bh) * PSTRIDE;
#pragma unroll
  for (int i = 0; i < 4; ++i) {
    float4 o; o.x = acc[i][0]; o.y = acc[i][1]; o.z = acc[i][2]; o.w = acc[i][3];
    *(float4*)(Pb + (size_t)(dkb + i) * DH + deb) = o;
  }
  if (t < 64) Pb[4096 + t] = zacc;
}

// ---------------- stage 2: reduce partials over chunks ---------------------
__global__ __launch_bounds__(256) void kvz_reduce(const float* __restrict__ P,
                                                  float* __restrict__ KV,
                                                  float* __restrict__ Z) {
  int bh = blockIdx.x;
  int t = threadIdx.x;
  for (int i = t; i < PSTRIDE; i += 256) {
    float s = 0.f;
#pragma unroll
    for (int c = 0; c < KVCH; ++c)
      s += P[((size_t)c * 64 + bh) * PSTRIDE + i];
    if (i < 4096) KV[(size_t)bh * 4096 + i] = s;
    else          Z[(size_t)bh * 64 + (i - 4096)] = s;
  }
}

// ---------------- attn (fp16 phiq in) -> fp16 ------------------------------
__global__ __launch_bounds__(256) void attn_kernel(const unsigned short* __restrict__ PQ,
                                                   const float* __restrict__ KVm,
                                                   const float* __restrict__ Z,
                                                   unsigned short* __restrict__ O) {
  int s0 = blockIdx.x << 6;
  int h = blockIdx.y, b = blockIdx.z;
  __shared__ float Pqt[64][64];
  __shared__ float Kv[64][64];
  __shared__ float den[64];
  __shared__ float zsh[64];
  int t = threadIdx.x;
  size_t qbase  = ((size_t)b * SEQ + s0) * D_MODEL + h * DH;
  size_t kvbase = (size_t)(b * NHEADS + h) * (DH * DH);
  int r0 = t >> 4;
  int c4 = (t & 15) << 2;
#pragma unroll
  for (int rr = 0; rr < 4; ++rr) {
    int row = r0 + (rr << 4);
    *(float4*)&Kv[row][c4] = *(const float4*)(KVm + kvbase + (size_t)row * DH + c4);
    ushort4 q = *(const ushort4*)(PQ + qbase + (size_t)row * D_MODEL + c4);
    Pqt[c4 + 0][row] = h2f(q.x);
    Pqt[c4 + 1][row] = h2f(q.y);
    Pqt[c4 + 2][row] = h2f(q.z);
    Pqt[c4 + 3][row] = h2f(q.w);
  }
  if (t < 16) *(float4*)&zsh[t << 2] = *(const float4*)(Z + (size_t)(b * NHEADS + h) * DH + (t << 2));
  __syncthreads();
  if (t < 64) {
    float d_ = 1e-6f;
#pragma unroll
    for (int dd = 0; dd < 64; ++dd) d_ += Pqt[dd][t] * zsh[dd];
    den[t] = d_;
  }
  __syncthreads();
  int tokb = (t >> 4) << 2, eb = (t & 15) << 2;
  float acc[4][4] = {};
#pragma unroll 8
  for (int dd = 0; dd < 64; ++dd) {
    float4 a  = *(const float4*)&Pqt[dd][tokb];
    float4 bb = *(const float4*)&Kv[dd][eb];
    acc[0][0] += a.x * bb.x; acc[0][1] += a.x * bb.y; acc[0][2] += a.x * bb.z; acc[0][3] += a.x * bb.w;
    acc[1][0] += a.y * bb.x; acc[1][1] += a.y * bb.y; acc[1][2] += a.y * bb.z; acc[1][3] += a.y * bb.w;
    acc[2][0] += a.z * bb.x; acc[2][1] += a.z * bb.y; acc[2][2] += a.z * bb.z; acc[2][3] += a.z * bb.w;
    acc[3][0] += a.w * bb.x; acc[3][1] += a.w * bb.y; acc[3][2] += a.w * bb.z; acc[3][3] += a.w * bb.w;
  }
#pragma unroll
  for (int i = 0; i < 4; ++i) {
    float dv = den[tokb + i];
    ushort4 hv;
    hv.x = f2h(acc[i][0] / dv);
    hv.y = f2h(acc[i][1] / dv);
    hv.z = f2h(acc[i][2] / dv);
    hv.w = f2h(acc[i][3] / dv);
    size_t oidx = ((size_t)b * SEQ + s0 + tokb + i) * D_MODEL + h * DH + eb;
    *(ushort4*)(O + oidx) = hv;
  }
}

extern "C" void kernel_launch(void* const* d_in, const int* in_sizes, int n_in,
                              void* d_out, int out_size, void* d_ws, size_t ws_size,
                              hipStream_t stream) {
  const float* x    = (const float*)d_in[0];
  const float* ln1g = (const float*)d_in[1];
  const float* ln1b = (const float*)d_in[2];
  const float* wq   = (const float*)d_in[3];
  const float* wk   = (const float*)d_in[4];
  const float* wv   = (const float*)d_in[5];
  const float* wo   = (const float*)d_in[6];
  const float* ln2g = (const float*)d_in[7];
  const float* ln2b = (const float*)d_in[8];
  const float* w1   = (const float*)d_in[9];
  const float* w2   = (const float*)d_in[10];
  float* out = (float*)d_out;
  char* ws = (char*)d_ws;

  const size_t MB = 1024 * 1024;
  unsigned short* xn   = (unsigned short*)(ws);
  unsigned short* qkv  = (unsigned short*)(ws + 32 * MB);  // phiq|phik|vbuf fp16
  unsigned short* phiq = qkv;
  unsigned short* phik = qkv + (size_t)NTOK * D_MODEL;
  unsigned short* vbuf = qkv + 2 * (size_t)NTOK * D_MODEL;
  unsigned short* ffn  = (unsigned short*)(ws + 32 * MB);  // overlays qkv slab
  unsigned short* w1T  = (unsigned short*)(ws + 96 * MB);
  unsigned short* w2T  = (unsigned short*)(ws + 104 * MB);
  unsigned short* woT  = (unsigned short*)(ws + 128 * MB);

  // d_out as scratch until wo-GEMM writes it
  unsigned short* wqkvT = (unsigned short*)d_out;          // [3072,1024] fp16
  float* kvP = (float*)((char*)d_out + 6 * MB);
  float* kv  = (float*)((char*)d_out + 24 * MB);
  float* z   = (float*)((char*)d_out + 25 * MB);

  dim3 blk(256);
  dim3 gcD(D_MODEL / 64, D_MODEL / 64);

  convT<<<gcD, blk, 0, stream>>>(wq, wqkvT, D_MODEL, D_MODEL);
  convT<<<gcD, blk, 0, stream>>>(wk, wqkvT + (size_t)D_MODEL * D_MODEL, D_MODEL, D_MODEL);
  convT<<<gcD, blk, 0, stream>>>(wv, wqkvT + 2 * (size_t)D_MODEL * D_MODEL, D_MODEL, D_MODEL);
  convT<<<gcD, blk, 0, stream>>>(wo, woT, D_MODEL, D_MODEL);

  ln_kernel<<<NTOK, blk, 0, stream>>>(x, ln1g, ln1b, xn);

  // fused qkv: C[8192,3072] -> phi(q),phi(k) | v, fp16 slabs
  dim3 gQKV(3 * D_MODEL / 128, NTOK / 128);
  mfma_gemm<4, 64><<<gQKV, blk, 0, stream>>>(xn, wqkvT, qkv, nullptr, 3 * D_MODEL, D_MODEL);

  kvz_partial<<<dim3(KVCH, BATCH * NHEADS), blk, 0, stream>>>(phik, vbuf, kvP);
  kvz_reduce<<<BATCH * NHEADS, blk, 0, stream>>>(kvP, kv, z);

  attn_kernel<<<dim3(SEQ / 64, NHEADS, BATCH), blk, 0, stream>>>(phiq, kv, z, xn);

  convT<<<dim3(DFF / 64, D_MODEL / 64), blk, 0, stream>>>(w1, w1T, D_MODEL, DFF);
  convT<<<dim3(D_MODEL / 64, DFF / 64), blk, 0, stream>>>(w2, w2T, DFF, D_MODEL);

  dim3 gD(D_MODEL / 128, NTOK / 128);
  // x1 = x + attn@wo -> out  (grid-starved: BK=128)
  mfma_gemm<2, 128><<<gD, blk, 0, stream>>>(xn, woT, out, x, D_MODEL, D_MODEL);

  ln_kernel<<<NTOK, blk, 0, stream>>>(out, ln2g, ln2b, xn);

  dim3 gF(DFF / 128, NTOK / 128);
  mfma_gemm<3, 64><<<gF, blk, 0, stream>>>(xn, w1T, ffn, nullptr, DFF, D_MODEL);

  // out += ffn @ w2  (grid-starved, K=4096: BK=128)
  mfma_gemm<2, 128><<<gD, blk, 0, stream>>>(ffn, w2T, out, out, D_MODEL, DFF);
}